// Round 8
// baseline (1301.207 us; speedup 1.0000x reference)
//
#include <hip/hip_runtime.h>
#include <hip/hip_fp16.h>
#include <math.h>

#define D 25
#define PH_STRIDE 32     // fp16 row padded to 32 elems = 64 B = one cache line
#define STATS_BLOCKS 512
#define NBK2 512         // max buckets of 512 nodes
#define BKT_SHIFT 9
#define BKT_MASK 511
#define BIN_EDGES 8192   // edges per bin block (256 thr x 32)
#define EPS 1e-5f

// ---------------- binA: per-(block,bucket) histogram ----------------
__global__ __launch_bounds__(256) void binA(const int* __restrict__ dst,
                                            int* __restrict__ hist2D, int E) {
    __shared__ int h[NBK2];
    h[threadIdx.x] = 0;
    h[threadIdx.x + 256] = 0;
    __syncthreads();
    int base = blockIdx.x * BIN_EDGES;
#pragma unroll
    for (int j = 0; j < 32; ++j) {
        int idx = base + j * 256 + threadIdx.x;
        if (idx < E) atomicAdd(&h[dst[idx] >> BKT_SHIFT], 1);
    }
    __syncthreads();
    hist2D[blockIdx.x * NBK2 + threadIdx.x] = h[threadIdx.x];
    hist2D[blockIdx.x * NBK2 + threadIdx.x + 256] = h[threadIdx.x + 256];
}

// ------- colscan: per bucket, exclusive scan over blocks (in place) + total -------
__global__ __launch_bounds__(512) void colscan(int* __restrict__ hist2D,
                                               int* __restrict__ bCount, int nbBin) {
    __shared__ int s[512];
    int b = blockIdx.x;
    int j = threadIdx.x;
    int v = (j < nbBin) ? hist2D[j * NBK2 + b] : 0;
    s[j] = v;
    __syncthreads();
    for (int off = 1; off < 512; off <<= 1) {
        int x = (j >= off) ? s[j - off] : 0;
        __syncthreads();
        s[j] += x;
        __syncthreads();
    }
    if (j < nbBin) hist2D[j * NBK2 + b] = s[j] - v;   // exclusive prefix
    if (j == 0) bCount[b] = s[511];
}

// ---------------- exclusive scan of bucket totals ----------------
__global__ __launch_bounds__(512) void bucket_scan(const int* __restrict__ bCount,
                                                   int* __restrict__ bBase) {
    __shared__ int s[NBK2];
    int t = threadIdx.x;
    s[t] = bCount[t];
    __syncthreads();
    for (int off = 1; off < NBK2; off <<= 1) {
        int x = (t >= off) ? s[t - off] : 0;
        __syncthreads();
        s[t] += x;
        __syncthreads();
    }
    bBase[t] = (t > 0) ? s[t - 1] : 0;
}

// ------- binB: write keys (src<<9 | dst&511) grouped by bucket -------
__global__ __launch_bounds__(256) void binB(const int* __restrict__ src,
                                            const int* __restrict__ dst,
                                            const int* __restrict__ hist2D,
                                            const int* __restrict__ bBase,
                                            int* __restrict__ binned, int E) {
    __shared__ int rank[NBK2], basew[NBK2];
    int t = threadIdx.x;
    rank[t] = 0; rank[t + 256] = 0;
    basew[t] = bBase[t] + hist2D[blockIdx.x * NBK2 + t];
    basew[t + 256] = bBase[t + 256] + hist2D[blockIdx.x * NBK2 + t + 256];
    __syncthreads();
    int base = blockIdx.x * BIN_EDGES;
#pragma unroll
    for (int j = 0; j < 32; ++j) {
        int idx = base + j * 256 + t;
        if (idx < E) {
            int d = dst[idx];
            int b = d >> BKT_SHIFT;
            int r = atomicAdd(&rank[b], 1);
            binned[basew[b] + r] = (src[idx] << BKT_SHIFT) | (d & BKT_MASK);
        }
    }
}

// ------- deg from binned: block per bucket, LDS hist, coalesced write -------
__global__ __launch_bounds__(256) void deg_bucket(const int* __restrict__ binned,
                                                  const int* __restrict__ bBase,
                                                  const int* __restrict__ bCount,
                                                  int* __restrict__ deg, int N) {
    int b = blockIdx.x;
    int nodeBase = b << BKT_SHIFT;
    __shared__ int h[NBK2];
    int t = threadIdx.x;
    h[t] = 0; h[t + 256] = 0;
    __syncthreads();
    int s = bBase[b], e = s + bCount[b];
    for (int k = s + t; k < e; k += 256)
        atomicAdd(&h[binned[k] & BKT_MASK], 1);
    __syncthreads();
    if (nodeBase + t < N) deg[nodeBase + t] = h[t];
    if (nodeBase + t + 256 < N) deg[nodeBase + t + 256] = h[t + 256];
}

// ------------- layer1 (fp16 rows): Ph = half(dinv * (emb[x] @ W1)), stride 32, pads=0 -------------
__global__ __launch_bounds__(256) void embed_gemm1_h(
        const int* __restrict__ x, const float* __restrict__ emb,
        const float* __restrict__ W1, const int* __restrict__ deg,
        __half* __restrict__ Ph, int N) {
    __shared__ float sW[D * D];
    for (int j = threadIdx.x; j < D * D; j += blockDim.x) sW[j] = W1[j];
    __syncthreads();
    int i = blockIdx.x * blockDim.x + threadIdx.x;
    if (i >= N) return;
    const float* er = emb + (size_t)x[i] * D;
    float t[D];
#pragma unroll
    for (int k = 0; k < D; ++k) t[k] = er[k];
    float dinv = rsqrtf((float)deg[i] + 1.0f);
    __half* row = Ph + (size_t)i * PH_STRIDE;
#pragma unroll
    for (int d = 0; d < D; ++d) {
        float acc = 0.0f;
#pragma unroll
        for (int k = 0; k < D; ++k) acc = fmaf(t[k], sW[k * D + d], acc);
        row[d] = __float2half(dinv * acc);
    }
#pragma unroll
    for (int d = D; d < PH_STRIDE; ++d) row[d] = __float2half(0.0f);
}

// ------- bgather: block per bucket; LDS accumulator; fused finish + BN stats -------
// acc[node][f] in LDS (512x25 fp32). 16-lane group per edge, LDS float atomics.
__global__ __launch_bounds__(256) void bgather(
        const int* __restrict__ binned, const int* __restrict__ bBase,
        const int* __restrict__ bCount, const int* __restrict__ deg,
        const __half* __restrict__ Ph, const float* __restrict__ bias,
        float* __restrict__ Q, float* __restrict__ st, int N) {
    __shared__ float acc[512 * D];          // 51.2 KB
    __shared__ float red[4][16][4];
    int t = threadIdx.x;
    for (int i = t; i < 512 * D; i += 256) acc[i] = 0.0f;
    __syncthreads();
    int b = blockIdx.x;
    int nodeBase = b << BKT_SHIFT;
    int s = bBase[b];
    int e = s + bCount[b];
    int g = t >> 4;        // group 0..15
    int f = t & 15;        // lane within group
    const __half2* rowb = (const __half2*)Ph;   // row stride = 16 half2
    int k = s + g;
    // 4 edges in flight per group
    for (; k + 48 < e; k += 64) {
        int k0 = binned[k], k1 = binned[k + 16], k2 = binned[k + 32], k3 = binned[k + 48];
        float2 v0 = __half22float2(rowb[((size_t)(k0 >> BKT_SHIFT) << 4) + f]);
        float2 v1 = __half22float2(rowb[((size_t)(k1 >> BKT_SHIFT) << 4) + f]);
        float2 v2 = __half22float2(rowb[((size_t)(k2 >> BKT_SHIFT) << 4) + f]);
        float2 v3 = __half22float2(rowb[((size_t)(k3 >> BKT_SHIFT) << 4) + f]);
        int d0 = (k0 & BKT_MASK) * D, d1 = (k1 & BKT_MASK) * D;
        int d2 = (k2 & BKT_MASK) * D, d3 = (k3 & BKT_MASK) * D;
        if (f < 12) {
            atomicAdd(&acc[d0 + 2 * f], v0.x); atomicAdd(&acc[d0 + 2 * f + 1], v0.y);
            atomicAdd(&acc[d1 + 2 * f], v1.x); atomicAdd(&acc[d1 + 2 * f + 1], v1.y);
            atomicAdd(&acc[d2 + 2 * f], v2.x); atomicAdd(&acc[d2 + 2 * f + 1], v2.y);
            atomicAdd(&acc[d3 + 2 * f], v3.x); atomicAdd(&acc[d3 + 2 * f + 1], v3.y);
        } else if (f == 12) {
            atomicAdd(&acc[d0 + 24], v0.x);
            atomicAdd(&acc[d1 + 24], v1.x);
            atomicAdd(&acc[d2 + 24], v2.x);
            atomicAdd(&acc[d3 + 24], v3.x);
        }
    }
    for (; k < e; k += 16) {
        int key = binned[k];
        float2 v = __half22float2(rowb[((size_t)(key >> BKT_SHIFT) << 4) + f]);
        int dl = (key & BKT_MASK) * D;
        if (f < 12) {
            atomicAdd(&acc[dl + 2 * f], v.x);
            atomicAdd(&acc[dl + 2 * f + 1], v.y);
        } else if (f == 12) {
            atomicAdd(&acc[dl + 24], v.x);
        }
    }
    __syncthreads();
    // finish: Q = dinv*(acc + self) + bias; local stats for features 2f, 2f+1
    float ls0 = 0.0f, lq0 = 0.0f, ls1 = 0.0f, lq1 = 0.0f;
    for (int n = g; n < 512; n += 16) {
        int node = nodeBase + n;
        if (node >= N) break;
        float2 pv = __half22float2(rowb[((size_t)node << 4) + f]);
        float dinv = rsqrtf((float)deg[node] + 1.0f);
        if (f < 12) {
            float q0 = fmaf(dinv, acc[n * D + 2 * f] + pv.x, bias[2 * f]);
            float q1 = fmaf(dinv, acc[n * D + 2 * f + 1] + pv.y, bias[2 * f + 1]);
            Q[(size_t)node * D + 2 * f] = q0;
            Q[(size_t)node * D + 2 * f + 1] = q1;
            ls0 += q0; lq0 += q0 * q0;
            ls1 += q1; lq1 += q1 * q1;
        } else if (f == 12) {
            float q0 = fmaf(dinv, acc[n * D + 24] + pv.x, bias[24]);
            Q[(size_t)node * D + 24] = q0;
            ls0 += q0; lq0 += q0 * q0;
        }
    }
    // reduce over the wave's 4 groups (lanes t, t+16, t+32, t+48)
    ls0 += __shfl_down(ls0, 32, 64); ls0 += __shfl_down(ls0, 16, 64);
    lq0 += __shfl_down(lq0, 32, 64); lq0 += __shfl_down(lq0, 16, 64);
    ls1 += __shfl_down(ls1, 32, 64); ls1 += __shfl_down(ls1, 16, 64);
    lq1 += __shfl_down(lq1, 32, 64); lq1 += __shfl_down(lq1, 16, 64);
    if ((t & 63) < 16) {
        int w = t >> 6;
        red[w][f][0] = ls0; red[w][f][1] = lq0;
        red[w][f][2] = ls1; red[w][f][3] = lq1;
    }
    __syncthreads();
    if (t < 64) {
        int ff = t >> 2, slot = t & 3;
        float tot = red[0][ff][slot] + red[1][ff][slot] + red[2][ff][slot] + red[3][ff][slot];
        int a = 2 * ff + (slot >> 1);
        if (a < D) atomicAdd(&st[a + (slot & 1) * D], tot);
    }
}

// ------- layer2 (fp16 rows): mu/rstd inline from st; t = relu(bn(Q)); Ph = half(dinv*(t@W2)) -------
__global__ __launch_bounds__(256) void bn_gemm_h(
        const float* __restrict__ Qin, const float* __restrict__ st, float invN,
        const float* __restrict__ g, const float* __restrict__ be,
        const float* __restrict__ W, const int* __restrict__ deg,
        __half* __restrict__ Ph, int N) {
    __shared__ float sW[D * D];
    __shared__ float sScale[D], sShift[D];
    for (int j = threadIdx.x; j < D * D; j += blockDim.x) sW[j] = W[j];
    if (threadIdx.x < D) {
        float m = st[threadIdx.x] * invN;
        float v = fmaxf(st[D + threadIdx.x] * invN - m * m, 0.0f);
        float sc = rsqrtf(v + EPS) * g[threadIdx.x];
        sScale[threadIdx.x] = sc;
        sShift[threadIdx.x] = be[threadIdx.x] - m * sc;
    }
    __syncthreads();
    int i = blockIdx.x * blockDim.x + threadIdx.x;
    if (i >= N) return;
    float t[D];
#pragma unroll
    for (int d = 0; d < D; ++d)
        t[d] = fmaxf(0.0f, fmaf(Qin[i * D + d], sScale[d], sShift[d]));
    float dinv = rsqrtf((float)deg[i] + 1.0f);
    __half* row = Ph + (size_t)i * PH_STRIDE;
#pragma unroll
    for (int d = 0; d < D; ++d) {
        float acc = 0.0f;
#pragma unroll
        for (int k = 0; k < D; ++k) acc = fmaf(t[k], sW[k * D + d], acc);
        row[d] = __float2half(dinv * acc);
    }
#pragma unroll
    for (int d = D; d < PH_STRIDE; ++d) row[d] = __float2half(0.0f);
}

// ------- head: mu/rstd inline from st; t = relu(bn(Q)); m = relu(t@Wm1+bm1); out = sigmoid -------
__global__ __launch_bounds__(256) void final_kernel(
        const float* __restrict__ Q, const float* __restrict__ st, float invN,
        const float* __restrict__ g, const float* __restrict__ be,
        const float* __restrict__ Wm1, const float* __restrict__ bm1,
        const float* __restrict__ Wm2, const float* __restrict__ bm2,
        float* __restrict__ out, int N) {
    __shared__ float sW1[D * 12];
    __shared__ float sb1[12], sW2[12];
    __shared__ float sScale[D], sShift[D];
    __shared__ float sb2;
    for (int j = threadIdx.x; j < D * 12; j += blockDim.x) sW1[j] = Wm1[j];
    if (threadIdx.x < 12) {
        sb1[threadIdx.x] = bm1[threadIdx.x];
        sW2[threadIdx.x] = Wm2[threadIdx.x];
    }
    if (threadIdx.x < D) {
        float m = st[threadIdx.x] * invN;
        float v = fmaxf(st[D + threadIdx.x] * invN - m * m, 0.0f);
        float sc = rsqrtf(v + EPS) * g[threadIdx.x];
        sScale[threadIdx.x] = sc;
        sShift[threadIdx.x] = be[threadIdx.x] - m * sc;
    }
    if (threadIdx.x == 0) sb2 = bm2[0];
    __syncthreads();
    int i = blockIdx.x * blockDim.x + threadIdx.x;
    if (i >= N) return;
    float t[D];
#pragma unroll
    for (int d = 0; d < D; ++d)
        t[d] = fmaxf(0.0f, fmaf(Q[i * D + d], sScale[d], sShift[d]));
    float z = sb2;
#pragma unroll
    for (int j = 0; j < 12; ++j) {
        float m = sb1[j];
#pragma unroll
        for (int k = 0; k < D; ++k) m = fmaf(t[k], sW1[k * 12 + j], m);
        m = fmaxf(0.0f, m);
        z = fmaf(m, sW2[j], z);
    }
    out[i] = 1.0f / (1.0f + expf(-z));
}

// ================= fallback kernels (atomic-scatter path) =================
__global__ void hist_kernel(const int* __restrict__ dst, int* __restrict__ deg, int E) {
    int e = blockIdx.x * blockDim.x + threadIdx.x;
    if (e < E) atomicAdd(&deg[dst[e]], 1);
}

__global__ __launch_bounds__(256) void embed_gemm1(
        const int* __restrict__ x, const float* __restrict__ emb,
        const float* __restrict__ W1, const int* __restrict__ deg,
        float* __restrict__ P, float* __restrict__ Qdup, int N) {
    __shared__ float sW[D * D];
    for (int j = threadIdx.x; j < D * D; j += blockDim.x) sW[j] = W1[j];
    __syncthreads();
    int i = blockIdx.x * blockDim.x + threadIdx.x;
    if (i >= N) return;
    const float* er = emb + (size_t)x[i] * D;
    float t[D];
#pragma unroll
    for (int k = 0; k < D; ++k) t[k] = er[k];
    float dinv = rsqrtf((float)deg[i] + 1.0f);
#pragma unroll
    for (int d = 0; d < D; ++d) {
        float acc = 0.0f;
#pragma unroll
        for (int k = 0; k < D; ++k) acc = fmaf(t[k], sW[k * D + d], acc);
        float v = dinv * acc;
        P[i * D + d] = v;
        if (Qdup) Qdup[i * D + d] = v;
    }
}

__global__ void scatter_kernel(const int* __restrict__ src, const int* __restrict__ dst,
                               const float* __restrict__ A, float* __restrict__ B, int E) {
    int idx = blockIdx.x * blockDim.x + threadIdx.x;
    int e = idx >> 5;
    int lane = idx & 31;
    if (e >= E || lane >= D) return;
    atomicAdd(&B[dst[e] * D + lane], A[src[e] * D + lane]);
}

__global__ __launch_bounds__(256) void transform_kernel(
        float* __restrict__ Q, const int* __restrict__ deg,
        const float* __restrict__ bias, int N) {
    int i = blockIdx.x * blockDim.x + threadIdx.x;
    if (i >= N) return;
    float dinv = rsqrtf((float)deg[i] + 1.0f);
#pragma unroll
    for (int d = 0; d < D; ++d)
        Q[i * D + d] = fmaf(dinv, Q[i * D + d], bias[d]);
}

__global__ __launch_bounds__(256) void bn_gemm(
        const float* __restrict__ Qin, const float* __restrict__ st, float invN,
        const float* __restrict__ g, const float* __restrict__ be,
        const float* __restrict__ W, const int* __restrict__ deg,
        float* __restrict__ P, float* __restrict__ Qdup, int N) {
    __shared__ float sW[D * D];
    __shared__ float sScale[D], sShift[D];
    for (int j = threadIdx.x; j < D * D; j += blockDim.x) sW[j] = W[j];
    if (threadIdx.x < D) {
        float m = st[threadIdx.x] * invN;
        float v = fmaxf(st[D + threadIdx.x] * invN - m * m, 0.0f);
        float sc = rsqrtf(v + EPS) * g[threadIdx.x];
        sScale[threadIdx.x] = sc;
        sShift[threadIdx.x] = be[threadIdx.x] - m * sc;
    }
    __syncthreads();
    int i = blockIdx.x * blockDim.x + threadIdx.x;
    if (i >= N) return;
    float t[D];
#pragma unroll
    for (int d = 0; d < D; ++d)
        t[d] = fmaxf(0.0f, fmaf(Qin[i * D + d], sScale[d], sShift[d]));
    float dinv = rsqrtf((float)deg[i] + 1.0f);
#pragma unroll
    for (int d = 0; d < D; ++d) {
        float acc = 0.0f;
#pragma unroll
        for (int k = 0; k < D; ++k) acc = fmaf(t[k], sW[k * D + d], acc);
        float v = dinv * acc;
        P[i * D + d] = v;
        if (Qdup) Qdup[i * D + d] = v;
    }
}

__global__ __launch_bounds__(256) void stats_kernel(
        const float* __restrict__ Q, float* __restrict__ st, int N) {
    float ls[D], lq[D];
#pragma unroll
    for (int d = 0; d < D; ++d) { ls[d] = 0.0f; lq[d] = 0.0f; }
    for (int i = blockIdx.x * blockDim.x + threadIdx.x; i < N;
         i += gridDim.x * blockDim.x) {
#pragma unroll
        for (int d = 0; d < D; ++d) {
            float v = Q[i * D + d];
            ls[d] += v;
            lq[d] += v * v;
        }
    }
#pragma unroll
    for (int d = 0; d < D; ++d) {
        for (int off = 32; off > 0; off >>= 1) {
            ls[d] += __shfl_down(ls[d], off, 64);
            lq[d] += __shfl_down(lq[d], off, 64);
        }
    }
    __shared__ float red[4][2 * D];
    int wave = threadIdx.x >> 6;
    int lane = threadIdx.x & 63;
    if (lane == 0) {
#pragma unroll
        for (int d = 0; d < D; ++d) {
            red[wave][d] = ls[d];
            red[wave][D + d] = lq[d];
        }
    }
    __syncthreads();
    if (threadIdx.x < 2 * D) {
        float t = red[0][threadIdx.x] + red[1][threadIdx.x] +
                  red[2][threadIdx.x] + red[3][threadIdx.x];
        atomicAdd(&st[threadIdx.x], t);
    }
}

extern "C" void kernel_launch(void* const* d_in, const int* in_sizes, int n_in,
                              void* d_out, int out_size, void* d_ws, size_t ws_size,
                              hipStream_t stream) {
    const int*   x    = (const int*)d_in[0];
    const int*   ei   = (const int*)d_in[1];
    const float* emb  = (const float*)d_in[2];
    const float* W1   = (const float*)d_in[3];
    const float* b1   = (const float*)d_in[4];
    const float* g1   = (const float*)d_in[5];
    const float* be1  = (const float*)d_in[6];
    const float* W2   = (const float*)d_in[7];
    const float* b2   = (const float*)d_in[8];
    const float* g2   = (const float*)d_in[9];
    const float* be2  = (const float*)d_in[10];
    const float* Wm1  = (const float*)d_in[11];
    const float* bm1  = (const float*)d_in[12];
    const float* Wm2  = (const float*)d_in[13];
    const float* bm2  = (const float*)d_in[14];
    float* out = (float*)d_out;

    int N = in_sizes[0];
    int E = in_sizes[1] / 2;
    const int* src = ei;
    const int* dst = ei + E;
    float invN = 1.0f / (float)N;

    int nbBin = (E + BIN_EDGES - 1) / BIN_EDGES;
    // words: deg N + binned E + bCount 512 + bBase 512 + hist2D nbBin*512 + Ph 16N + Q 25N + st 100
    size_t need = ((size_t)42 * N + E + 1024 + (size_t)nbBin * NBK2 + 100) * 4;
    bool useBin = (ws_size >= need) && (N <= NBK2 * 512) && (nbBin <= 512);

    int nbN  = (N + 255) / 256;
    int nbE  = (E + 255) / 256;
    int nbS  = (int)(((long)E * 32 + 255) / 256);
    int nbBkt = (N + 511) / 512;

    if (useBin) {
        int*    deg    = (int*)d_ws;                    // N
        int*    binned = deg + N;                       // E
        int*    bCount = binned + E;                    // 512
        int*    bBase  = bCount + NBK2;                 // 512
        int*    hist2D = bBase + NBK2;                  // nbBin*512
        __half* Ph     = (__half*)(hist2D + (size_t)nbBin * NBK2);   // N*32 halves
        float*  Q      = (float*)(Ph + (size_t)N * PH_STRIDE);       // N*25
        float*  stats  = Q + (size_t)N * D;             // 100
        float* st1 = stats;
        float* st2 = stats + 50;

        hipMemsetAsync(stats, 0, 100 * sizeof(float), stream);

        binA<<<nbBin, 256, 0, stream>>>(dst, hist2D, E);
        colscan<<<NBK2, 512, 0, stream>>>(hist2D, bCount, nbBin);
        bucket_scan<<<1, NBK2, 0, stream>>>(bCount, bBase);
        binB<<<nbBin, 256, 0, stream>>>(src, dst, hist2D, bBase, binned, E);
        deg_bucket<<<nbBkt, 256, 0, stream>>>(binned, bBase, bCount, deg, N);
        embed_gemm1_h<<<nbN, 256, 0, stream>>>(x, emb, W1, deg, Ph, N);
        bgather<<<nbBkt, 256, 0, stream>>>(binned, bBase, bCount, deg, Ph, b1, Q, st1, N);
        bn_gemm_h<<<nbN, 256, 0, stream>>>(Q, st1, invN, g1, be1, W2, deg, Ph, N);
        bgather<<<nbBkt, 256, 0, stream>>>(binned, bBase, bCount, deg, Ph, b2, Q, st2, N);
        final_kernel<<<nbN, 256, 0, stream>>>(Q, st2, invN, g2, be2, Wm1, bm1, Wm2, bm2, out, N);
    } else {
        // fallback: fp32 atomic-scatter path
        int*   deg   = (int*)d_ws;                  // N
        float* P     = (float*)(deg + N);           // N*D
        float* Q     = P + (size_t)N * D;           // N*D
        float* stats = Q + (size_t)N * D;           // 100
        float* st1 = stats;
        float* st2 = stats + 50;

        hipMemsetAsync(deg, 0, (size_t)N * sizeof(int), stream);
        hipMemsetAsync(stats, 0, 100 * sizeof(float), stream);

        hist_kernel<<<nbE, 256, 0, stream>>>(dst, deg, E);
        embed_gemm1<<<nbN, 256, 0, stream>>>(x, emb, W1, deg, P, Q, N);
        scatter_kernel<<<nbS, 256, 0, stream>>>(src, dst, P, Q, E);
        transform_kernel<<<nbN, 256, 0, stream>>>(Q, deg, b1, N);
        stats_kernel<<<STATS_BLOCKS, 256, 0, stream>>>(Q, st1, N);
        bn_gemm<<<nbN, 256, 0, stream>>>(Q, st1, invN, g1, be1, W2, deg, P, Q, N);
        scatter_kernel<<<nbS, 256, 0, stream>>>(src, dst, P, Q, E);
        transform_kernel<<<nbN, 256, 0, stream>>>(Q, deg, b2, N);
        stats_kernel<<<STATS_BLOCKS, 256, 0, stream>>>(Q, st2, N);
        final_kernel<<<nbN, 256, 0, stream>>>(Q, st2, invN, g2, be2, Wm1, bm1, Wm2, bm2, out, N);
    }
}

// Round 9
// 365.665 us; speedup vs baseline: 3.5585x; 3.5585x over previous
//
#include <hip/hip_runtime.h>
#include <hip/hip_fp16.h>
#include <math.h>

#define D 25
#define PH_STRIDE 32    // fp16 row padded to 32 elems = 64 B = one cache line
#define STATS_BLOCKS 512
#define NBK 256         // buckets of 1024 nodes
#define BIN_EDGES 8192  // edges per bin block (256 thr x 32)
#define EPS 1e-5f

// ---------------- binA: per-(block,bucket) histogram, no global atomics ----------------
__global__ __launch_bounds__(256) void binA(const int* __restrict__ dst,
                                            int* __restrict__ hist2D, int E) {
    __shared__ int h[NBK];
    h[threadIdx.x] = 0;
    __syncthreads();
    int base = blockIdx.x * BIN_EDGES;
#pragma unroll
    for (int j = 0; j < 32; ++j) {
        int idx = base + j * 256 + threadIdx.x;
        if (idx < E) atomicAdd(&h[dst[idx] >> 10], 1);
    }
    __syncthreads();
    hist2D[blockIdx.x * NBK + threadIdx.x] = h[threadIdx.x];
}

// ------- colscan: per bucket, exclusive scan over blocks (in place) + total -------
__global__ __launch_bounds__(512) void colscan(int* __restrict__ hist2D,
                                               int* __restrict__ bCount, int nbBin) {
    __shared__ int s[512];
    int b = blockIdx.x;
    int j = threadIdx.x;
    int v = (j < nbBin) ? hist2D[j * NBK + b] : 0;
    s[j] = v;
    __syncthreads();
    for (int off = 1; off < 512; off <<= 1) {
        int x = (j >= off) ? s[j - off] : 0;
        __syncthreads();
        s[j] += x;
        __syncthreads();
    }
    if (j < nbBin) hist2D[j * NBK + b] = s[j] - v;   // exclusive prefix
    if (j == 0) bCount[b] = s[511];
}

// ------- binB: inline 256-scan of bCount for bases; write keys grouped by bucket -------
__global__ __launch_bounds__(256) void binB(const int* __restrict__ src,
                                            const int* __restrict__ dst,
                                            const int* __restrict__ hist2D,
                                            const int* __restrict__ bCount,
                                            int* __restrict__ binned, int E) {
    __shared__ int rank[NBK], basew[NBK], sc[NBK];
    int t = threadIdx.x;
    int cnt = bCount[t];
    sc[t] = cnt;
    rank[t] = 0;
    __syncthreads();
    for (int off = 1; off < NBK; off <<= 1) {
        int x = (t >= off) ? sc[t - off] : 0;
        __syncthreads();
        sc[t] += x;
        __syncthreads();
    }
    basew[t] = (sc[t] - cnt) + hist2D[blockIdx.x * NBK + t];
    __syncthreads();
    int base = blockIdx.x * BIN_EDGES;
#pragma unroll
    for (int j = 0; j < 32; ++j) {
        int idx = base + j * 256 + t;
        if (idx < E) {
            int d = dst[idx];
            int b = d >> 10;
            int r = atomicAdd(&rank[b], 1);
            binned[basew[b] + r] = (src[idx] << 10) | (d & 1023);
        }
    }
}

// ------- per-bucket CSR fill (512 threads): block b owns nodes [b*1024,(b+1)*1024) -------
__global__ __launch_bounds__(512) void bucket_fill(const int* __restrict__ binned,
                                                   const int* __restrict__ bCount,
                                                   int* __restrict__ degi, int* __restrict__ cursor,
                                                   int* __restrict__ csr, int N) {
    int b = blockIdx.x;
    int nodeBase = b << 10;
    if (nodeBase >= N) return;
    __shared__ int h[1024];
    __shared__ int s2[512];
    __shared__ int sBase;
    int t = threadIdx.x;
    if (t == 0) {
        int acc = 0;
        for (int i = 0; i < b; ++i) acc += bCount[i];   // 256 reads, L2-hot; one thread
        sBase = acc;
    }
    h[t] = 0; h[t + 512] = 0;
    __syncthreads();
    int s = sBase;
    int e = s + bCount[b];
    for (int k = s + t; k < e; k += 512)
        atomicAdd(&h[binned[k] & 1023], 1);
    __syncthreads();
    int i0 = t * 2;
    int v0 = h[i0], v1 = h[i0 + 1];
    int node0 = nodeBase + i0;
    if (node0 < N) degi[node0] = v0;
    if (node0 + 1 < N) degi[node0 + 1] = v1;
    s2[t] = v0 + v1;
    __syncthreads();
    for (int off = 1; off < 512; off <<= 1) {
        int x = (t >= off) ? s2[t - off] : 0;
        __syncthreads();
        s2[t] += x;
        __syncthreads();
    }
    int pre = (t > 0) ? s2[t - 1] : 0;
    h[i0] = pre;
    h[i0 + 1] = pre + v0;
    __syncthreads();
    for (int k = s + t; k < e; k += 512) {
        int key = binned[k];
        int p = atomicAdd(&h[key & 1023], 1);
        csr[s + p] = key >> 10;
    }
    __syncthreads();
    if (node0 < N) cursor[node0] = s + h[i0];
    if (node0 + 1 < N) cursor[node0 + 1] = s + h[i0 + 1];
}

// ---------------- fallback degree histogram ----------------
__global__ void hist_kernel(const int* __restrict__ dst, int* __restrict__ degi, int E) {
    int e = blockIdx.x * blockDim.x + threadIdx.x;
    if (e < E) atomicAdd(&degi[dst[e]], 1);
}

// ------------- layer1 (fp16 rows): Ph = half(dinv * (emb[x] @ W1)), stride 32, pads=0 -------------
__global__ __launch_bounds__(256) void embed_gemm1_h(
        const int* __restrict__ x, const float* __restrict__ emb,
        const float* __restrict__ W1, const int* __restrict__ degi,
        __half* __restrict__ Ph, int N) {
    __shared__ float sW[D * D];
    for (int j = threadIdx.x; j < D * D; j += blockDim.x) sW[j] = W1[j];
    __syncthreads();
    int i = blockIdx.x * blockDim.x + threadIdx.x;
    if (i >= N) return;
    const float* er = emb + (size_t)x[i] * D;
    float t[D];
#pragma unroll
    for (int k = 0; k < D; ++k) t[k] = er[k];
    float dinv = rsqrtf((float)degi[i] + 1.0f);
    __half* row = Ph + (size_t)i * PH_STRIDE;
#pragma unroll
    for (int d = 0; d < D; ++d) {
        float acc = 0.0f;
#pragma unroll
        for (int k = 0; k < D; ++k) acc = fmaf(t[k], sW[k * D + d], acc);
        row[d] = __float2half(dinv * acc);
    }
#pragma unroll
    for (int d = D; d < PH_STRIDE; ++d) row[d] = __float2half(0.0f);
}

// ------- gather: 16-lane walk per node, 4 nodes per wave, 8 edges in flight per walk -------
__global__ __launch_bounds__(256) void gather_finish_w8(
        const int* __restrict__ csr, const int* __restrict__ cursor,
        const int* __restrict__ degi, const __half* __restrict__ Ph,
        const float* __restrict__ bias, float* __restrict__ Q, int N) {
    int node = blockIdx.x * 16 + (threadIdx.x >> 4);
    if (node >= N) return;
    int f = threadIdx.x & 15;                 // half2 index within the 64B row
    int end = cursor[node];
    int dg = degi[node];
    int k = end - dg;
    const __half2* rowb = (const __half2*)Ph; // row stride = 16 half2
    float2 sv = __half22float2(rowb[((size_t)node << 4) + f]);  // self loop
    float ax = sv.x, ay = sv.y;
    for (; k + 8 <= end; k += 8) {
        int s0 = csr[k],     s1 = csr[k + 1], s2 = csr[k + 2], s3 = csr[k + 3];
        int s4 = csr[k + 4], s5 = csr[k + 5], s6 = csr[k + 6], s7 = csr[k + 7];
        float2 v0 = __half22float2(rowb[((size_t)s0 << 4) + f]);
        float2 v1 = __half22float2(rowb[((size_t)s1 << 4) + f]);
        float2 v2 = __half22float2(rowb[((size_t)s2 << 4) + f]);
        float2 v3 = __half22float2(rowb[((size_t)s3 << 4) + f]);
        float2 v4 = __half22float2(rowb[((size_t)s4 << 4) + f]);
        float2 v5 = __half22float2(rowb[((size_t)s5 << 4) + f]);
        float2 v6 = __half22float2(rowb[((size_t)s6 << 4) + f]);
        float2 v7 = __half22float2(rowb[((size_t)s7 << 4) + f]);
        ax += ((v0.x + v1.x) + (v2.x + v3.x)) + ((v4.x + v5.x) + (v6.x + v7.x));
        ay += ((v0.y + v1.y) + (v2.y + v3.y)) + ((v4.y + v5.y) + (v6.y + v7.y));
    }
    for (; k + 4 <= end; k += 4) {
        int s0 = csr[k], s1 = csr[k + 1], s2 = csr[k + 2], s3 = csr[k + 3];
        float2 v0 = __half22float2(rowb[((size_t)s0 << 4) + f]);
        float2 v1 = __half22float2(rowb[((size_t)s1 << 4) + f]);
        float2 v2 = __half22float2(rowb[((size_t)s2 << 4) + f]);
        float2 v3 = __half22float2(rowb[((size_t)s3 << 4) + f]);
        ax += (v0.x + v1.x) + (v2.x + v3.x);
        ay += (v0.y + v1.y) + (v2.y + v3.y);
    }
    for (; k < end; ++k) {
        float2 v = __half22float2(rowb[((size_t)csr[k] << 4) + f]);
        ax += v.x; ay += v.y;
    }
    if (f < 13) {
        float dinv = rsqrtf((float)dg + 1.0f);
        int j0 = f << 1;
        Q[(size_t)node * D + j0] = fmaf(dinv, ax, bias[j0]);
        if (f < 12) Q[(size_t)node * D + j0 + 1] = fmaf(dinv, ay, bias[j0 + 1]);
    }
}

// ------- layer2 (fp16 rows): mu/rstd inline from st; t = relu(bn(Q)); Ph = half(dinv*(t@W2)) -------
__global__ __launch_bounds__(256) void bn_gemm_h(
        const float* __restrict__ Qin, const float* __restrict__ st, float invN,
        const float* __restrict__ g, const float* __restrict__ be,
        const float* __restrict__ W, const int* __restrict__ degi,
        __half* __restrict__ Ph, int N) {
    __shared__ float sW[D * D];
    __shared__ float sScale[D], sShift[D];
    for (int j = threadIdx.x; j < D * D; j += blockDim.x) sW[j] = W[j];
    if (threadIdx.x < D) {
        float m = st[threadIdx.x] * invN;
        float v = fmaxf(st[D + threadIdx.x] * invN - m * m, 0.0f);
        float sc = rsqrtf(v + EPS) * g[threadIdx.x];
        sScale[threadIdx.x] = sc;
        sShift[threadIdx.x] = be[threadIdx.x] - m * sc;
    }
    __syncthreads();
    int i = blockIdx.x * blockDim.x + threadIdx.x;
    if (i >= N) return;
    float t[D];
#pragma unroll
    for (int d = 0; d < D; ++d)
        t[d] = fmaxf(0.0f, fmaf(Qin[i * D + d], sScale[d], sShift[d]));
    float dinv = rsqrtf((float)degi[i] + 1.0f);
    __half* row = Ph + (size_t)i * PH_STRIDE;
#pragma unroll
    for (int d = 0; d < D; ++d) {
        float acc = 0.0f;
#pragma unroll
        for (int k = 0; k < D; ++k) acc = fmaf(t[k], sW[k * D + d], acc);
        row[d] = __float2half(dinv * acc);
    }
#pragma unroll
    for (int d = D; d < PH_STRIDE; ++d) row[d] = __float2half(0.0f);
}

// ---------------- fp32 fallback kernels (atomic-scatter path) ----------------
__global__ __launch_bounds__(256) void embed_gemm1(
        const int* __restrict__ x, const float* __restrict__ emb,
        const float* __restrict__ W1, const int* __restrict__ degi,
        float* __restrict__ P, float* __restrict__ Qdup, int N) {
    __shared__ float sW[D * D];
    for (int j = threadIdx.x; j < D * D; j += blockDim.x) sW[j] = W1[j];
    __syncthreads();
    int i = blockIdx.x * blockDim.x + threadIdx.x;
    if (i >= N) return;
    const float* er = emb + (size_t)x[i] * D;
    float t[D];
#pragma unroll
    for (int k = 0; k < D; ++k) t[k] = er[k];
    float dinv = rsqrtf((float)degi[i] + 1.0f);
#pragma unroll
    for (int d = 0; d < D; ++d) {
        float acc = 0.0f;
#pragma unroll
        for (int k = 0; k < D; ++k) acc = fmaf(t[k], sW[k * D + d], acc);
        float v = dinv * acc;
        P[i * D + d] = v;
        if (Qdup) Qdup[i * D + d] = v;
    }
}

__global__ void scatter_kernel(const int* __restrict__ src, const int* __restrict__ dst,
                               const float* __restrict__ A, float* __restrict__ B, int E) {
    int idx = blockIdx.x * blockDim.x + threadIdx.x;
    int e = idx >> 5;
    int lane = idx & 31;
    if (e >= E || lane >= D) return;
    atomicAdd(&B[dst[e] * D + lane], A[src[e] * D + lane]);
}

__global__ __launch_bounds__(256) void transform_kernel(
        float* __restrict__ Q, const int* __restrict__ degi,
        const float* __restrict__ bias, int N) {
    int i = blockIdx.x * blockDim.x + threadIdx.x;
    if (i >= N) return;
    float dinv = rsqrtf((float)degi[i] + 1.0f);
#pragma unroll
    for (int d = 0; d < D; ++d)
        Q[i * D + d] = fmaf(dinv, Q[i * D + d], bias[d]);
}

__global__ __launch_bounds__(256) void bn_gemm(
        const float* __restrict__ Qin, const float* __restrict__ st, float invN,
        const float* __restrict__ g, const float* __restrict__ be,
        const float* __restrict__ W, const int* __restrict__ degi,
        float* __restrict__ P, float* __restrict__ Qdup, int N) {
    __shared__ float sW[D * D];
    __shared__ float sScale[D], sShift[D];
    for (int j = threadIdx.x; j < D * D; j += blockDim.x) sW[j] = W[j];
    if (threadIdx.x < D) {
        float m = st[threadIdx.x] * invN;
        float v = fmaxf(st[D + threadIdx.x] * invN - m * m, 0.0f);
        float sc = rsqrtf(v + EPS) * g[threadIdx.x];
        sScale[threadIdx.x] = sc;
        sShift[threadIdx.x] = be[threadIdx.x] - m * sc;
    }
    __syncthreads();
    int i = blockIdx.x * blockDim.x + threadIdx.x;
    if (i >= N) return;
    float t[D];
#pragma unroll
    for (int d = 0; d < D; ++d)
        t[d] = fmaxf(0.0f, fmaf(Qin[i * D + d], sScale[d], sShift[d]));
    float dinv = rsqrtf((float)degi[i] + 1.0f);
#pragma unroll
    for (int d = 0; d < D; ++d) {
        float acc = 0.0f;
#pragma unroll
        for (int k = 0; k < D; ++k) acc = fmaf(t[k], sW[k * D + d], acc);
        float v = dinv * acc;
        P[i * D + d] = v;
        if (Qdup) Qdup[i * D + d] = v;
    }
}

// ---------------- stats over Q: st[0..24]=sum, st[25..49]=sumsq ----------------
__global__ __launch_bounds__(256) void stats_kernel(
        const float* __restrict__ Q, float* __restrict__ st, int N) {
    float ls[D], lq[D];
#pragma unroll
    for (int d = 0; d < D; ++d) { ls[d] = 0.0f; lq[d] = 0.0f; }
    for (int i = blockIdx.x * blockDim.x + threadIdx.x; i < N;
         i += gridDim.x * blockDim.x) {
#pragma unroll
        for (int d = 0; d < D; ++d) {
            float v = Q[i * D + d];
            ls[d] += v;
            lq[d] += v * v;
        }
    }
#pragma unroll
    for (int d = 0; d < D; ++d) {
        for (int off = 32; off > 0; off >>= 1) {
            ls[d] += __shfl_down(ls[d], off, 64);
            lq[d] += __shfl_down(lq[d], off, 64);
        }
    }
    __shared__ float red[4][2 * D];
    int wave = threadIdx.x >> 6;
    int lane = threadIdx.x & 63;
    if (lane == 0) {
#pragma unroll
        for (int d = 0; d < D; ++d) {
            red[wave][d] = ls[d];
            red[wave][D + d] = lq[d];
        }
    }
    __syncthreads();
    if (threadIdx.x < 2 * D) {
        float t = red[0][threadIdx.x] + red[1][threadIdx.x] +
                  red[2][threadIdx.x] + red[3][threadIdx.x];
        atomicAdd(&st[threadIdx.x], t);
    }
}

// ------- head: mu/rstd inline from st; t = relu(bn(Q)); m = relu(t@Wm1+bm1); out = sigmoid -------
__global__ __launch_bounds__(256) void final_kernel(
        const float* __restrict__ Q, const float* __restrict__ st, float invN,
        const float* __restrict__ g, const float* __restrict__ be,
        const float* __restrict__ Wm1, const float* __restrict__ bm1,
        const float* __restrict__ Wm2, const float* __restrict__ bm2,
        float* __restrict__ out, int N) {
    __shared__ float sW1[D * 12];
    __shared__ float sb1[12], sW2[12];
    __shared__ float sScale[D], sShift[D];
    __shared__ float sb2;
    for (int j = threadIdx.x; j < D * 12; j += blockDim.x) sW1[j] = Wm1[j];
    if (threadIdx.x < 12) {
        sb1[threadIdx.x] = bm1[threadIdx.x];
        sW2[threadIdx.x] = Wm2[threadIdx.x];
    }
    if (threadIdx.x < D) {
        float m = st[threadIdx.x] * invN;
        float v = fmaxf(st[D + threadIdx.x] * invN - m * m, 0.0f);
        float sc = rsqrtf(v + EPS) * g[threadIdx.x];
        sScale[threadIdx.x] = sc;
        sShift[threadIdx.x] = be[threadIdx.x] - m * sc;
    }
    if (threadIdx.x == 0) sb2 = bm2[0];
    __syncthreads();
    int i = blockIdx.x * blockDim.x + threadIdx.x;
    if (i >= N) return;
    float t[D];
#pragma unroll
    for (int d = 0; d < D; ++d)
        t[d] = fmaxf(0.0f, fmaf(Q[i * D + d], sScale[d], sShift[d]));
    float z = sb2;
#pragma unroll
    for (int j = 0; j < 12; ++j) {
        float m = sb1[j];
#pragma unroll
        for (int k = 0; k < D; ++k) m = fmaf(t[k], sW1[k * 12 + j], m);
        m = fmaxf(0.0f, m);
        z = fmaf(m, sW2[j], z);
    }
    out[i] = 1.0f / (1.0f + expf(-z));
}

extern "C" void kernel_launch(void* const* d_in, const int* in_sizes, int n_in,
                              void* d_out, int out_size, void* d_ws, size_t ws_size,
                              hipStream_t stream) {
    const int*   x    = (const int*)d_in[0];
    const int*   ei   = (const int*)d_in[1];
    const float* emb  = (const float*)d_in[2];
    const float* W1   = (const float*)d_in[3];
    const float* b1   = (const float*)d_in[4];
    const float* g1   = (const float*)d_in[5];
    const float* be1  = (const float*)d_in[6];
    const float* W2   = (const float*)d_in[7];
    const float* b2   = (const float*)d_in[8];
    const float* g2   = (const float*)d_in[9];
    const float* be2  = (const float*)d_in[10];
    const float* Wm1  = (const float*)d_in[11];
    const float* bm1  = (const float*)d_in[12];
    const float* Wm2  = (const float*)d_in[13];
    const float* bm2  = (const float*)d_in[14];
    float* out = (float*)d_out;

    int N = in_sizes[0];
    int E = in_sizes[1] / 2;
    const int* src = ei;
    const int* dst = ei + E;
    float invN = 1.0f / (float)N;

    int nbBin = (E + BIN_EDGES - 1) / BIN_EDGES;
    size_t csrNeed = ((size_t)43 * N + E + 512 + (size_t)nbBin * NBK + 200) * 4;
    bool useCSR = (ws_size >= csrNeed) && (N <= NBK * 1024) && (nbBin <= 512) &&
                  ((size_t)E <= (size_t)N * D);

    int nbN  = (N + 255) / 256;
    int nbE  = (E + 255) / 256;
    int nbG  = (N + 15) / 16;            // 16 nodes per 256-thread block
    int nbS  = (int)(((long)E * 32 + 255) / 256);

    if (useCSR) {
        int*    degi    = (int*)d_ws;                   // N
        int*    cursor  = degi + N;                     // N
        int*    csr     = cursor + N;                   // E
        int*    bCount  = csr + E;                      // 256
        int*    bBase   = bCount + NBK;                 // 256 (unused, kept for layout)
        int*    hist2D  = bBase + NBK;                  // nbBin*256
        __half* Ph      = (__half*)(hist2D + (size_t)nbBin * NBK);   // N*32 halves
        float*  Q       = (float*)(Ph + (size_t)N * PH_STRIDE);      // N*25
        float*  stats   = Q + (size_t)N * D;            // 100
        int*    binned  = (int*)Q;                      // E ints (aliases Q; dead before Q written)
        float* st1 = stats;
        float* st2 = stats + 50;

        hipMemsetAsync(stats, 0, 100 * sizeof(float), stream);

        int nbBkt = (N + 1023) / 1024;

        binA<<<nbBin, 256, 0, stream>>>(dst, hist2D, E);
        colscan<<<NBK, 512, 0, stream>>>(hist2D, bCount, nbBin);
        binB<<<nbBin, 256, 0, stream>>>(src, dst, hist2D, bCount, binned, E);
        bucket_fill<<<nbBkt, 512, 0, stream>>>(binned, bCount, degi, cursor, csr, N);
        embed_gemm1_h<<<nbN, 256, 0, stream>>>(x, emb, W1, degi, Ph, N);
        gather_finish_w8<<<nbG, 256, 0, stream>>>(csr, cursor, degi, Ph, b1, Q, N);
        stats_kernel<<<STATS_BLOCKS, 256, 0, stream>>>(Q, st1, N);
        bn_gemm_h<<<nbN, 256, 0, stream>>>(Q, st1, invN, g1, be1, W2, degi, Ph, N);
        gather_finish_w8<<<nbG, 256, 0, stream>>>(csr, cursor, degi, Ph, b2, Q, N);
        stats_kernel<<<STATS_BLOCKS, 256, 0, stream>>>(Q, st2, N);
        final_kernel<<<nbN, 256, 0, stream>>>(Q, st2, invN, g2, be2, Wm1, bm1, Wm2, bm2, out, N);
    } else {
        // fallback: fp32 atomic-scatter path
        int*   degi  = (int*)d_ws;                  // N
        float* P     = (float*)(degi + N);          // N*D
        float* Q     = P + (size_t)N * D;           // N*D
        float* stats = Q + (size_t)N * D;           // 100
        float* st1 = stats;
        float* st2 = stats + 50;

        hipMemsetAsync(degi, 0, (size_t)N * sizeof(int), stream);
        hipMemsetAsync(stats, 0, 100 * sizeof(float), stream);

        hist_kernel<<<nbE, 256, 0, stream>>>(dst, degi, E);
        embed_gemm1<<<nbN, 256, 0, stream>>>(x, emb, W1, degi, P, Q, N);
        scatter_kernel<<<nbS, 256, 0, stream>>>(src, dst, P, Q, E);
        transform_kernel<<<nbN, 256, 0, stream>>>(Q, degi, b1, N);
        stats_kernel<<<STATS_BLOCKS, 256, 0, stream>>>(Q, st1, N);
        bn_gemm<<<nbN, 256, 0, stream>>>(Q, st1, invN, g1, be1, W2, degi, P, Q, N);
        scatter_kernel<<<nbS, 256, 0, stream>>>(src, dst, P, Q, E);
        transform_kernel<<<nbN, 256, 0, stream>>>(Q, degi, b2, N);
        stats_kernel<<<STATS_BLOCKS, 256, 0, stream>>>(Q, st2, N);
        final_kernel<<<nbN, 256, 0, stream>>>(Q, st2, invN, g2, be2, Wm1, bm1, Wm2, bm2, out, N);
    }
}

// Round 10
// 335.666 us; speedup vs baseline: 3.8765x; 1.0894x over previous
//
#include <hip/hip_runtime.h>
#include <hip/hip_fp16.h>
#include <math.h>

#define D 25
#define PH_STRIDE 32    // fp16 row padded to 32 elems = 64 B = one cache line
#define STATS_BLOCKS 512
#define NBK 256         // buckets of 1024 nodes
#define BIN_EDGES 8192  // edges per bin block (256 thr x 32)
#define NSLOT 64        // replicated stat partial slots
#define EPS 1e-5f

// ---------------- binA: per-(block,bucket) histogram, no global atomics ----------------
__global__ __launch_bounds__(256) void binA(const int* __restrict__ dst,
                                            int* __restrict__ hist2D, int E) {
    __shared__ int h[NBK];
    h[threadIdx.x] = 0;
    __syncthreads();
    int base = blockIdx.x * BIN_EDGES;
#pragma unroll
    for (int j = 0; j < 32; ++j) {
        int idx = base + j * 256 + threadIdx.x;
        if (idx < E) atomicAdd(&h[dst[idx] >> 10], 1);
    }
    __syncthreads();
    hist2D[blockIdx.x * NBK + threadIdx.x] = h[threadIdx.x];
}

// ------- colscan: per bucket, exclusive scan over blocks (in place) + total -------
__global__ __launch_bounds__(512) void colscan(int* __restrict__ hist2D,
                                               int* __restrict__ bCount, int nbBin) {
    __shared__ int s[512];
    int b = blockIdx.x;
    int j = threadIdx.x;
    int v = (j < nbBin) ? hist2D[j * NBK + b] : 0;
    s[j] = v;
    __syncthreads();
    for (int off = 1; off < 512; off <<= 1) {
        int x = (j >= off) ? s[j - off] : 0;
        __syncthreads();
        s[j] += x;
        __syncthreads();
    }
    if (j < nbBin) hist2D[j * NBK + b] = s[j] - v;   // exclusive prefix
    if (j == 0) bCount[b] = s[511];
}

// ------- binB: inline 256-scan of bCount for bases; write keys grouped by bucket -------
__global__ __launch_bounds__(256) void binB(const int* __restrict__ src,
                                            const int* __restrict__ dst,
                                            const int* __restrict__ hist2D,
                                            const int* __restrict__ bCount,
                                            int* __restrict__ binned, int E) {
    __shared__ int rank[NBK], basew[NBK], sc[NBK];
    int t = threadIdx.x;
    int cnt = bCount[t];
    sc[t] = cnt;
    rank[t] = 0;
    __syncthreads();
    for (int off = 1; off < NBK; off <<= 1) {
        int x = (t >= off) ? sc[t - off] : 0;
        __syncthreads();
        sc[t] += x;
        __syncthreads();
    }
    basew[t] = (sc[t] - cnt) + hist2D[blockIdx.x * NBK + t];
    __syncthreads();
    int base = blockIdx.x * BIN_EDGES;
#pragma unroll
    for (int j = 0; j < 32; ++j) {
        int idx = base + j * 256 + t;
        if (idx < E) {
            int d = dst[idx];
            int b = d >> 10;
            int r = atomicAdd(&rank[b], 1);
            binned[basew[b] + r] = (src[idx] << 10) | (d & 1023);
        }
    }
}

// ------- per-bucket CSR fill (512 threads): block b owns nodes [b*1024,(b+1)*1024) -------
__global__ __launch_bounds__(512) void bucket_fill(const int* __restrict__ binned,
                                                   const int* __restrict__ bCount,
                                                   int* __restrict__ degi, int* __restrict__ cursor,
                                                   int* __restrict__ csr, int N) {
    int b = blockIdx.x;
    int nodeBase = b << 10;
    if (nodeBase >= N) return;
    __shared__ int h[1024];
    __shared__ int s2[512];
    int t = threadIdx.x;
    // parallel reduce of bCount[0..b-1] into base
    if (t < 256) s2[t] = (t < b) ? bCount[t] : 0;
    __syncthreads();
    for (int off = 128; off > 0; off >>= 1) {
        if (t < off) s2[t] += s2[t + off];
        __syncthreads();
    }
    int s = s2[0];
    __syncthreads();
    h[t] = 0; h[t + 512] = 0;
    __syncthreads();
    int e = s + bCount[b];
    for (int k = s + t; k < e; k += 512)
        atomicAdd(&h[binned[k] & 1023], 1);
    __syncthreads();
    int i0 = t * 2;
    int v0 = h[i0], v1 = h[i0 + 1];
    int node0 = nodeBase + i0;
    if (node0 < N) degi[node0] = v0;
    if (node0 + 1 < N) degi[node0 + 1] = v1;
    s2[t] = v0 + v1;
    __syncthreads();
    for (int off = 1; off < 512; off <<= 1) {
        int x = (t >= off) ? s2[t - off] : 0;
        __syncthreads();
        s2[t] += x;
        __syncthreads();
    }
    int pre = (t > 0) ? s2[t - 1] : 0;
    h[i0] = pre;
    h[i0 + 1] = pre + v0;
    __syncthreads();
    for (int k = s + t; k < e; k += 512) {
        int key = binned[k];
        int p = atomicAdd(&h[key & 1023], 1);
        csr[s + p] = key >> 10;
    }
    __syncthreads();
    if (node0 < N) cursor[node0] = s + h[i0];
    if (node0 + 1 < N) cursor[node0 + 1] = s + h[i0 + 1];
}

// ---------------- fallback degree histogram ----------------
__global__ void hist_kernel(const int* __restrict__ dst, int* __restrict__ degi, int E) {
    int e = blockIdx.x * blockDim.x + threadIdx.x;
    if (e < E) atomicAdd(&degi[dst[e]], 1);
}

// ------------- layer1 (fp16 rows): Ph = half(dinv * (emb[x] @ W1)), stride 32, pads=0 -------------
__global__ __launch_bounds__(256) void embed_gemm1_h(
        const int* __restrict__ x, const float* __restrict__ emb,
        const float* __restrict__ W1, const int* __restrict__ degi,
        __half* __restrict__ Ph, int N) {
    __shared__ float sW[D * D];
    for (int j = threadIdx.x; j < D * D; j += blockDim.x) sW[j] = W1[j];
    __syncthreads();
    int i = blockIdx.x * blockDim.x + threadIdx.x;
    if (i >= N) return;
    const float* er = emb + (size_t)x[i] * D;
    float t[D];
#pragma unroll
    for (int k = 0; k < D; ++k) t[k] = er[k];
    float dinv = rsqrtf((float)degi[i] + 1.0f);
    __half* row = Ph + (size_t)i * PH_STRIDE;
#pragma unroll
    for (int d = 0; d < D; ++d) {
        float acc = 0.0f;
#pragma unroll
        for (int k = 0; k < D; ++k) acc = fmaf(t[k], sW[k * D + d], acc);
        row[d] = __float2half(dinv * acc);
    }
#pragma unroll
    for (int d = D; d < PH_STRIDE; ++d) row[d] = __float2half(0.0f);
}

// ------- gather + fused BN-stats: 16-lane walk per node, 8 edges in flight;
//         block-level stat partials -> stPart[blockIdx%64][50] -------
__global__ __launch_bounds__(256) void gather_stats_w8(
        const int* __restrict__ csr, const int* __restrict__ cursor,
        const int* __restrict__ degi, const __half* __restrict__ Ph,
        const float* __restrict__ bias, float* __restrict__ Q,
        float* __restrict__ stPart, int N) {
    int t = threadIdx.x;
    int node = blockIdx.x * 16 + (t >> 4);
    int f = t & 15;                 // half2 index within the 64B row
    const __half2* rowb = (const __half2*)Ph; // row stride = 16 half2
    float q0 = 0.0f, q1 = 0.0f;
    bool act = (node < N);
    if (act) {
        int end = cursor[node];
        int dg = degi[node];
        int k = end - dg;
        float2 sv = __half22float2(rowb[((size_t)node << 4) + f]);  // self loop
        float ax = sv.x, ay = sv.y;
        for (; k + 8 <= end; k += 8) {
            int s0 = csr[k],     s1 = csr[k + 1], s2 = csr[k + 2], s3 = csr[k + 3];
            int s4 = csr[k + 4], s5 = csr[k + 5], s6 = csr[k + 6], s7 = csr[k + 7];
            float2 v0 = __half22float2(rowb[((size_t)s0 << 4) + f]);
            float2 v1 = __half22float2(rowb[((size_t)s1 << 4) + f]);
            float2 v2 = __half22float2(rowb[((size_t)s2 << 4) + f]);
            float2 v3 = __half22float2(rowb[((size_t)s3 << 4) + f]);
            float2 v4 = __half22float2(rowb[((size_t)s4 << 4) + f]);
            float2 v5 = __half22float2(rowb[((size_t)s5 << 4) + f]);
            float2 v6 = __half22float2(rowb[((size_t)s6 << 4) + f]);
            float2 v7 = __half22float2(rowb[((size_t)s7 << 4) + f]);
            ax += ((v0.x + v1.x) + (v2.x + v3.x)) + ((v4.x + v5.x) + (v6.x + v7.x));
            ay += ((v0.y + v1.y) + (v2.y + v3.y)) + ((v4.y + v5.y) + (v6.y + v7.y));
        }
        for (; k + 4 <= end; k += 4) {
            int s0 = csr[k], s1 = csr[k + 1], s2 = csr[k + 2], s3 = csr[k + 3];
            float2 v0 = __half22float2(rowb[((size_t)s0 << 4) + f]);
            float2 v1 = __half22float2(rowb[((size_t)s1 << 4) + f]);
            float2 v2 = __half22float2(rowb[((size_t)s2 << 4) + f]);
            float2 v3 = __half22float2(rowb[((size_t)s3 << 4) + f]);
            ax += (v0.x + v1.x) + (v2.x + v3.x);
            ay += (v0.y + v1.y) + (v2.y + v3.y);
        }
        for (; k < end; ++k) {
            float2 v = __half22float2(rowb[((size_t)csr[k] << 4) + f]);
            ax += v.x; ay += v.y;
        }
        float dinv = rsqrtf((float)dg + 1.0f);
        if (f < 13) {
            int j0 = f << 1;
            q0 = fmaf(dinv, ax, bias[j0]);
            Q[(size_t)node * D + j0] = q0;
            if (f < 12) {
                q1 = fmaf(dinv, ay, bias[j0 + 1]);
                Q[(size_t)node * D + j0 + 1] = q1;
            }
        }
    }
    // ---- fused BN stats: reduce this block's 16 nodes ----
    float ls0 = q0, lq0 = q0 * q0, ls1 = q1, lq1 = q1 * q1;
    ls0 += __shfl_down(ls0, 32, 64); ls0 += __shfl_down(ls0, 16, 64);
    lq0 += __shfl_down(lq0, 32, 64); lq0 += __shfl_down(lq0, 16, 64);
    ls1 += __shfl_down(ls1, 32, 64); ls1 += __shfl_down(ls1, 16, 64);
    lq1 += __shfl_down(lq1, 32, 64); lq1 += __shfl_down(lq1, 16, 64);
    __shared__ float red[4][16][4];
    if ((t & 63) < 16) {
        int w = t >> 6;
        red[w][f][0] = ls0; red[w][f][1] = lq0;
        red[w][f][2] = ls1; red[w][f][3] = lq1;
    }
    __syncthreads();
    if (t < 64) {
        int ff = t >> 2, slot = t & 3;
        float tot = red[0][ff][slot] + red[1][ff][slot] + red[2][ff][slot] + red[3][ff][slot];
        int a = 2 * ff + (slot >> 1);
        if (a < D) atomicAdd(&stPart[(blockIdx.x & (NSLOT - 1)) * 50 + a + (slot & 1) * D], tot);
    }
}

// ------- layer2: reduce stPart -> mu/rstd; t = relu(bn(Q)); Ph = half(dinv*(t@W2)) -------
__global__ __launch_bounds__(256) void bn_gemm_hp(
        const float* __restrict__ Qin, const float* __restrict__ stPart, float invN,
        const float* __restrict__ g, const float* __restrict__ be,
        const float* __restrict__ W, const int* __restrict__ degi,
        __half* __restrict__ Ph, int N) {
    __shared__ float sW[D * D];
    __shared__ float sScale[D], sShift[D];
    __shared__ float sSum[2 * D];
    for (int j = threadIdx.x; j < D * D; j += blockDim.x) sW[j] = W[j];
    if (threadIdx.x < 2 * D) {
        float a = 0.0f;
        for (int k = 0; k < NSLOT; ++k) a += stPart[k * 50 + threadIdx.x];
        sSum[threadIdx.x] = a;
    }
    __syncthreads();
    if (threadIdx.x < D) {
        float m = sSum[threadIdx.x] * invN;
        float v = fmaxf(sSum[D + threadIdx.x] * invN - m * m, 0.0f);
        float sc = rsqrtf(v + EPS) * g[threadIdx.x];
        sScale[threadIdx.x] = sc;
        sShift[threadIdx.x] = be[threadIdx.x] - m * sc;
    }
    __syncthreads();
    int i = blockIdx.x * blockDim.x + threadIdx.x;
    if (i >= N) return;
    float t[D];
#pragma unroll
    for (int d = 0; d < D; ++d)
        t[d] = fmaxf(0.0f, fmaf(Qin[i * D + d], sScale[d], sShift[d]));
    float dinv = rsqrtf((float)degi[i] + 1.0f);
    __half* row = Ph + (size_t)i * PH_STRIDE;
#pragma unroll
    for (int d = 0; d < D; ++d) {
        float acc = 0.0f;
#pragma unroll
        for (int k = 0; k < D; ++k) acc = fmaf(t[k], sW[k * D + d], acc);
        row[d] = __float2half(dinv * acc);
    }
#pragma unroll
    for (int d = D; d < PH_STRIDE; ++d) row[d] = __float2half(0.0f);
}

// ------- head: reduce stPart -> mu/rstd; t = relu(bn(Q)); MLP; sigmoid -------
__global__ __launch_bounds__(256) void final_kernel_p(
        const float* __restrict__ Q, const float* __restrict__ stPart, float invN,
        const float* __restrict__ g, const float* __restrict__ be,
        const float* __restrict__ Wm1, const float* __restrict__ bm1,
        const float* __restrict__ Wm2, const float* __restrict__ bm2,
        float* __restrict__ out, int N) {
    __shared__ float sW1[D * 12];
    __shared__ float sb1[12], sW2[12];
    __shared__ float sScale[D], sShift[D];
    __shared__ float sSum[2 * D];
    __shared__ float sb2;
    for (int j = threadIdx.x; j < D * 12; j += blockDim.x) sW1[j] = Wm1[j];
    if (threadIdx.x < 12) {
        sb1[threadIdx.x] = bm1[threadIdx.x];
        sW2[threadIdx.x] = Wm2[threadIdx.x];
    }
    if (threadIdx.x < 2 * D) {
        float a = 0.0f;
        for (int k = 0; k < NSLOT; ++k) a += stPart[k * 50 + threadIdx.x];
        sSum[threadIdx.x] = a;
    }
    if (threadIdx.x == 0) sb2 = bm2[0];
    __syncthreads();
    if (threadIdx.x < D) {
        float m = sSum[threadIdx.x] * invN;
        float v = fmaxf(sSum[D + threadIdx.x] * invN - m * m, 0.0f);
        float sc = rsqrtf(v + EPS) * g[threadIdx.x];
        sScale[threadIdx.x] = sc;
        sShift[threadIdx.x] = be[threadIdx.x] - m * sc;
    }
    __syncthreads();
    int i = blockIdx.x * blockDim.x + threadIdx.x;
    if (i >= N) return;
    float t[D];
#pragma unroll
    for (int d = 0; d < D; ++d)
        t[d] = fmaxf(0.0f, fmaf(Q[i * D + d], sScale[d], sShift[d]));
    float z = sb2;
#pragma unroll
    for (int j = 0; j < 12; ++j) {
        float m = sb1[j];
#pragma unroll
        for (int k = 0; k < D; ++k) m = fmaf(t[k], sW1[k * 12 + j], m);
        m = fmaxf(0.0f, m);
        z = fmaf(m, sW2[j], z);
    }
    out[i] = 1.0f / (1.0f + expf(-z));
}

// ================= fallback kernels (atomic-scatter path, plain 50-float stats) =================
__global__ __launch_bounds__(256) void embed_gemm1(
        const int* __restrict__ x, const float* __restrict__ emb,
        const float* __restrict__ W1, const int* __restrict__ degi,
        float* __restrict__ P, float* __restrict__ Qdup, int N) {
    __shared__ float sW[D * D];
    for (int j = threadIdx.x; j < D * D; j += blockDim.x) sW[j] = W1[j];
    __syncthreads();
    int i = blockIdx.x * blockDim.x + threadIdx.x;
    if (i >= N) return;
    const float* er = emb + (size_t)x[i] * D;
    float t[D];
#pragma unroll
    for (int k = 0; k < D; ++k) t[k] = er[k];
    float dinv = rsqrtf((float)degi[i] + 1.0f);
#pragma unroll
    for (int d = 0; d < D; ++d) {
        float acc = 0.0f;
#pragma unroll
        for (int k = 0; k < D; ++k) acc = fmaf(t[k], sW[k * D + d], acc);
        float v = dinv * acc;
        P[i * D + d] = v;
        if (Qdup) Qdup[i * D + d] = v;
    }
}

__global__ void scatter_kernel(const int* __restrict__ src, const int* __restrict__ dst,
                               const float* __restrict__ A, float* __restrict__ B, int E) {
    int idx = blockIdx.x * blockDim.x + threadIdx.x;
    int e = idx >> 5;
    int lane = idx & 31;
    if (e >= E || lane >= D) return;
    atomicAdd(&B[dst[e] * D + lane], A[src[e] * D + lane]);
}

__global__ __launch_bounds__(256) void transform_kernel(
        float* __restrict__ Q, const int* __restrict__ degi,
        const float* __restrict__ bias, int N) {
    int i = blockIdx.x * blockDim.x + threadIdx.x;
    if (i >= N) return;
    float dinv = rsqrtf((float)degi[i] + 1.0f);
#pragma unroll
    for (int d = 0; d < D; ++d)
        Q[i * D + d] = fmaf(dinv, Q[i * D + d], bias[d]);
}

__global__ __launch_bounds__(256) void stats_kernel(
        const float* __restrict__ Q, float* __restrict__ st, int N) {
    float ls[D], lq[D];
#pragma unroll
    for (int d = 0; d < D; ++d) { ls[d] = 0.0f; lq[d] = 0.0f; }
    for (int i = blockIdx.x * blockDim.x + threadIdx.x; i < N;
         i += gridDim.x * blockDim.x) {
#pragma unroll
        for (int d = 0; d < D; ++d) {
            float v = Q[i * D + d];
            ls[d] += v;
            lq[d] += v * v;
        }
    }
#pragma unroll
    for (int d = 0; d < D; ++d) {
        for (int off = 32; off > 0; off >>= 1) {
            ls[d] += __shfl_down(ls[d], off, 64);
            lq[d] += __shfl_down(lq[d], off, 64);
        }
    }
    __shared__ float red[4][2 * D];
    int wave = threadIdx.x >> 6;
    int lane = threadIdx.x & 63;
    if (lane == 0) {
#pragma unroll
        for (int d = 0; d < D; ++d) {
            red[wave][d] = ls[d];
            red[wave][D + d] = lq[d];
        }
    }
    __syncthreads();
    if (threadIdx.x < 2 * D) {
        float t = red[0][threadIdx.x] + red[1][threadIdx.x] +
                  red[2][threadIdx.x] + red[3][threadIdx.x];
        atomicAdd(&st[threadIdx.x], t);
    }
}

__global__ __launch_bounds__(256) void bn_gemm(
        const float* __restrict__ Qin, const float* __restrict__ st, float invN,
        const float* __restrict__ g, const float* __restrict__ be,
        const float* __restrict__ W, const int* __restrict__ degi,
        float* __restrict__ P, float* __restrict__ Qdup, int N) {
    __shared__ float sW[D * D];
    __shared__ float sScale[D], sShift[D];
    for (int j = threadIdx.x; j < D * D; j += blockDim.x) sW[j] = W[j];
    if (threadIdx.x < D) {
        float m = st[threadIdx.x] * invN;
        float v = fmaxf(st[D + threadIdx.x] * invN - m * m, 0.0f);
        float sc = rsqrtf(v + EPS) * g[threadIdx.x];
        sScale[threadIdx.x] = sc;
        sShift[threadIdx.x] = be[threadIdx.x] - m * sc;
    }
    __syncthreads();
    int i = blockIdx.x * blockDim.x + threadIdx.x;
    if (i >= N) return;
    float t[D];
#pragma unroll
    for (int d = 0; d < D; ++d)
        t[d] = fmaxf(0.0f, fmaf(Qin[i * D + d], sScale[d], sShift[d]));
    float dinv = rsqrtf((float)degi[i] + 1.0f);
#pragma unroll
    for (int d = 0; d < D; ++d) {
        float acc = 0.0f;
#pragma unroll
        for (int k = 0; k < D; ++k) acc = fmaf(t[k], sW[k * D + d], acc);
        float v = dinv * acc;
        P[i * D + d] = v;
        if (Qdup) Qdup[i * D + d] = v;
    }
}

__global__ __launch_bounds__(256) void final_kernel(
        const float* __restrict__ Q, const float* __restrict__ st, float invN,
        const float* __restrict__ g, const float* __restrict__ be,
        const float* __restrict__ Wm1, const float* __restrict__ bm1,
        const float* __restrict__ Wm2, const float* __restrict__ bm2,
        float* __restrict__ out, int N) {
    __shared__ float sW1[D * 12];
    __shared__ float sb1[12], sW2[12];
    __shared__ float sScale[D], sShift[D];
    __shared__ float sb2;
    for (int j = threadIdx.x; j < D * 12; j += blockDim.x) sW1[j] = Wm1[j];
    if (threadIdx.x < 12) {
        sb1[threadIdx.x] = bm1[threadIdx.x];
        sW2[threadIdx.x] = Wm2[threadIdx.x];
    }
    if (threadIdx.x < D) {
        float m = st[threadIdx.x] * invN;
        float v = fmaxf(st[D + threadIdx.x] * invN - m * m, 0.0f);
        float sc = rsqrtf(v + EPS) * g[threadIdx.x];
        sScale[threadIdx.x] = sc;
        sShift[threadIdx.x] = be[threadIdx.x] - m * sc;
    }
    if (threadIdx.x == 0) sb2 = bm2[0];
    __syncthreads();
    int i = blockIdx.x * blockDim.x + threadIdx.x;
    if (i >= N) return;
    float t[D];
#pragma unroll
    for (int d = 0; d < D; ++d)
        t[d] = fmaxf(0.0f, fmaf(Q[i * D + d], sScale[d], sShift[d]));
    float z = sb2;
#pragma unroll
    for (int j = 0; j < 12; ++j) {
        float m = sb1[j];
#pragma unroll
        for (int k = 0; k < D; ++k) m = fmaf(t[k], sW1[k * 12 + j], m);
        m = fmaxf(0.0f, m);
        z = fmaf(m, sW2[j], z);
    }
    out[i] = 1.0f / (1.0f + expf(-z));
}

extern "C" void kernel_launch(void* const* d_in, const int* in_sizes, int n_in,
                              void* d_out, int out_size, void* d_ws, size_t ws_size,
                              hipStream_t stream) {
    const int*   x    = (const int*)d_in[0];
    const int*   ei   = (const int*)d_in[1];
    const float* emb  = (const float*)d_in[2];
    const float* W1   = (const float*)d_in[3];
    const float* b1   = (const float*)d_in[4];
    const float* g1   = (const float*)d_in[5];
    const float* be1  = (const float*)d_in[6];
    const float* W2   = (const float*)d_in[7];
    const float* b2   = (const float*)d_in[8];
    const float* g2   = (const float*)d_in[9];
    const float* be2  = (const float*)d_in[10];
    const float* Wm1  = (const float*)d_in[11];
    const float* bm1  = (const float*)d_in[12];
    const float* Wm2  = (const float*)d_in[13];
    const float* bm2  = (const float*)d_in[14];
    float* out = (float*)d_out;

    int N = in_sizes[0];
    int E = in_sizes[1] / 2;
    const int* src = ei;
    const int* dst = ei + E;
    float invN = 1.0f / (float)N;

    int nbBin = (E + BIN_EDGES - 1) / BIN_EDGES;
    // words: degi N + cursor N + csr E + bCount 256 + hist2D nbBin*256 + Ph 16N + Q 25N + stPart 2*64*50
    size_t csrNeed = ((size_t)43 * N + E + 256 + (size_t)nbBin * NBK + 2 * NSLOT * 50) * 4;
    bool useCSR = (ws_size >= csrNeed) && (N <= NBK * 1024) && (nbBin <= 512) &&
                  ((size_t)E <= (size_t)N * D);

    int nbN  = (N + 255) / 256;
    int nbE  = (E + 255) / 256;
    int nbG  = (N + 15) / 16;            // 16 nodes per 256-thread block
    int nbS  = (int)(((long)E * 32 + 255) / 256);

    if (useCSR) {
        int*    degi    = (int*)d_ws;                   // N
        int*    cursor  = degi + N;                     // N
        int*    csr     = cursor + N;                   // E
        int*    bCount  = csr + E;                      // 256
        int*    hist2D  = bCount + NBK;                 // nbBin*256
        __half* Ph      = (__half*)(hist2D + (size_t)nbBin * NBK);   // N*32 halves
        float*  Q       = (float*)(Ph + (size_t)N * PH_STRIDE);      // N*25
        float*  stP1    = Q + (size_t)N * D;            // 64*50
        float*  stP2    = stP1 + NSLOT * 50;            // 64*50
        int*    binned  = (int*)Q;                      // E ints (aliases Q; dead before Q written)

        hipMemsetAsync(stP1, 0, 2 * NSLOT * 50 * sizeof(float), stream);

        int nbBkt = (N + 1023) / 1024;

        binA<<<nbBin, 256, 0, stream>>>(dst, hist2D, E);
        colscan<<<NBK, 512, 0, stream>>>(hist2D, bCount, nbBin);
        binB<<<nbBin, 256, 0, stream>>>(src, dst, hist2D, bCount, binned, E);
        bucket_fill<<<nbBkt, 512, 0, stream>>>(binned, bCount, degi, cursor, csr, N);
        embed_gemm1_h<<<nbN, 256, 0, stream>>>(x, emb, W1, degi, Ph, N);
        gather_stats_w8<<<nbG, 256, 0, stream>>>(csr, cursor, degi, Ph, b1, Q, stP1, N);
        bn_gemm_hp<<<nbN, 256, 0, stream>>>(Q, stP1, invN, g1, be1, W2, degi, Ph, N);
        gather_stats_w8<<<nbG, 256, 0, stream>>>(csr, cursor, degi, Ph, b2, Q, stP2, N);
        final_kernel_p<<<nbN, 256, 0, stream>>>(Q, stP2, invN, g2, be2, Wm1, bm1, Wm2, bm2, out, N);
    } else {
        // fallback: fp32 atomic-scatter path
        int*   degi  = (int*)d_ws;                  // N
        float* P     = (float*)(degi + N);          // N*D
        float* Q     = P + (size_t)N * D;           // N*D
        float* stats = Q + (size_t)N * D;           // 100
        float* st1 = stats;
        float* st2 = stats + 50;

        hipMemsetAsync(degi, 0, (size_t)N * sizeof(int), stream);
        hipMemsetAsync(stats, 0, 100 * sizeof(float), stream);

        hist_kernel<<<nbE, 256, 0, stream>>>(dst, degi, E);
        embed_gemm1<<<nbN, 256, 0, stream>>>(x, emb, W1, degi, P, Q, N);
        scatter_kernel<<<nbS, 256, 0, stream>>>(src, dst, P, Q, E);
        transform_kernel<<<nbN, 256, 0, stream>>>(Q, degi, b1, N);
        stats_kernel<<<STATS_BLOCKS, 256, 0, stream>>>(Q, st1, N);
        bn_gemm<<<nbN, 256, 0, stream>>>(Q, st1, invN, g1, be1, W2, degi, P, Q, N);
        scatter_kernel<<<nbS, 256, 0, stream>>>(src, dst, P, Q, E);
        transform_kernel<<<nbN, 256, 0, stream>>>(Q, degi, b2, N);
        stats_kernel<<<STATS_BLOCKS, 256, 0, stream>>>(Q, st2, N);
        final_kernel<<<nbN, 256, 0, stream>>>(Q, st2, invN, g2, be2, Wm1, bm1, Wm2, bm2, out, N);
    }
}

// Round 11
// 332.352 us; speedup vs baseline: 3.9151x; 1.0100x over previous
//
#include <hip/hip_runtime.h>
#include <hip/hip_fp16.h>
#include <math.h>

#define D 25
#define PH_STRIDE 32    // fp16 row padded to 32 elems = 64 B = one cache line
#define STATS_BLOCKS 512
#define NBK 256         // buckets of 1024 nodes
#define BIN_EDGES 8192  // edges per bin block (256 thr x 32)
#define NSLOT 64        // replicated stat partial slots
#define EPS 1e-5f

// ---------------- binA: per-(block,bucket) histogram + stPart zeroing ----------------
__global__ __launch_bounds__(256) void binA(const int* __restrict__ dst,
                                            int* __restrict__ hist2D,
                                            float* __restrict__ stPart, int E) {
    // first 25 blocks zero the 2*NSLOT*50 = 6400-float stat partials
    if (blockIdx.x < 25) stPart[blockIdx.x * 256 + threadIdx.x] = 0.0f;
    __shared__ int h[NBK];
    h[threadIdx.x] = 0;
    __syncthreads();
    int base = blockIdx.x * BIN_EDGES;
#pragma unroll
    for (int j = 0; j < 32; ++j) {
        int idx = base + j * 256 + threadIdx.x;
        if (idx < E) atomicAdd(&h[dst[idx] >> 10], 1);
    }
    __syncthreads();
    hist2D[blockIdx.x * NBK + threadIdx.x] = h[threadIdx.x];
}

// ------- colscan: per bucket, exclusive scan over blocks (in place) + total -------
__global__ __launch_bounds__(512) void colscan(int* __restrict__ hist2D,
                                               int* __restrict__ bCount, int nbBin) {
    __shared__ int s[512];
    int b = blockIdx.x;
    int j = threadIdx.x;
    int v = (j < nbBin) ? hist2D[j * NBK + b] : 0;
    s[j] = v;
    __syncthreads();
    for (int off = 1; off < 512; off <<= 1) {
        int x = (j >= off) ? s[j - off] : 0;
        __syncthreads();
        s[j] += x;
        __syncthreads();
    }
    if (j < nbBin) hist2D[j * NBK + b] = s[j] - v;   // exclusive prefix
    if (j == 0) bCount[b] = s[511];
}

// ------- binB: inline 256-scan of bCount for bases; write keys grouped by bucket -------
__global__ __launch_bounds__(256) void binB(const int* __restrict__ src,
                                            const int* __restrict__ dst,
                                            const int* __restrict__ hist2D,
                                            const int* __restrict__ bCount,
                                            int* __restrict__ binned, int E) {
    __shared__ int rank[NBK], basew[NBK], sc[NBK];
    int t = threadIdx.x;
    int cnt = bCount[t];
    sc[t] = cnt;
    rank[t] = 0;
    __syncthreads();
    for (int off = 1; off < NBK; off <<= 1) {
        int x = (t >= off) ? sc[t - off] : 0;
        __syncthreads();
        sc[t] += x;
        __syncthreads();
    }
    basew[t] = (sc[t] - cnt) + hist2D[blockIdx.x * NBK + t];
    __syncthreads();
    int base = blockIdx.x * BIN_EDGES;
#pragma unroll
    for (int j = 0; j < 32; ++j) {
        int idx = base + j * 256 + t;
        if (idx < E) {
            int d = dst[idx];
            int b = d >> 10;
            int r = atomicAdd(&rank[b], 1);
            binned[basew[b] + r] = (src[idx] << 10) | (d & 1023);
        }
    }
}

// ------- fill_embed (512 thr): CSR fill for bucket b + fused layer-1 embed GEMM -------
__global__ __launch_bounds__(512) void fill_embed(
        const int* __restrict__ binned, const int* __restrict__ bCount,
        const int* __restrict__ x, const float* __restrict__ emb,
        const float* __restrict__ W1,
        int* __restrict__ degi, int* __restrict__ cursor, int* __restrict__ csr,
        __half* __restrict__ Ph, int N) {
    int b = blockIdx.x;
    int nodeBase = b << 10;
    if (nodeBase >= N) return;
    __shared__ int h[1024];
    __shared__ int s2[512];
    __shared__ float sW[D * D];
    int t = threadIdx.x;
    // parallel reduce of bCount[0..b-1] into base
    if (t < 256) s2[t] = (t < b) ? bCount[t] : 0;
    for (int j = t; j < D * D; j += 512) sW[j] = W1[j];
    __syncthreads();
    for (int off = 128; off > 0; off >>= 1) {
        if (t < 128 && t < off) s2[t] += s2[t + off];
        __syncthreads();
    }
    int s = s2[0];
    __syncthreads();
    h[t] = 0; h[t + 512] = 0;
    __syncthreads();
    int e = s + bCount[b];
    for (int k = s + t; k < e; k += 512)
        atomicAdd(&h[binned[k] & 1023], 1);
    __syncthreads();
    int i0 = t * 2;
    int v0 = h[i0], v1 = h[i0 + 1];
    int node0 = nodeBase + i0;
    if (node0 < N) degi[node0] = v0;
    if (node0 + 1 < N) degi[node0 + 1] = v1;
    s2[t] = v0 + v1;
    __syncthreads();
    for (int off = 1; off < 512; off <<= 1) {
        int xx = (t >= off) ? s2[t - off] : 0;
        __syncthreads();
        s2[t] += xx;
        __syncthreads();
    }
    int pre = (t > 0) ? s2[t - 1] : 0;
    h[i0] = pre;
    h[i0 + 1] = pre + v0;
    __syncthreads();
    for (int k = s + t; k < e; k += 512) {
        int key = binned[k];
        int p = atomicAdd(&h[key & 1023], 1);
        csr[s + p] = key >> 10;
    }
    __syncthreads();
    if (node0 < N) cursor[node0] = s + h[i0];
    if (node0 + 1 < N) cursor[node0 + 1] = s + h[i0 + 1];
    // ---- fused embed GEMM for this bucket's nodes (2 per thread) ----
#pragma unroll
    for (int which = 0; which < 2; ++which) {
        int node = node0 + which;
        if (node >= N) break;
        int dg = which ? v1 : v0;
        const float* er = emb + (size_t)x[node] * D;
        float tv[D];
#pragma unroll
        for (int k = 0; k < D; ++k) tv[k] = er[k];
        float dinv = rsqrtf((float)dg + 1.0f);
        __half* row = Ph + (size_t)node * PH_STRIDE;
#pragma unroll
        for (int d = 0; d < D; ++d) {
            float acc = 0.0f;
#pragma unroll
            for (int k = 0; k < D; ++k) acc = fmaf(tv[k], sW[k * D + d], acc);
            row[d] = __float2half(dinv * acc);
        }
#pragma unroll
        for (int d = D; d < PH_STRIDE; ++d) row[d] = __float2half(0.0f);
    }
}

// ------- gather + fused BN-stats: 16-lane walk per node, 8 edges in flight;
//         Q stored as fp16 rows (stride 32); stPart[blockIdx%64][50] -------
__global__ __launch_bounds__(256) void gather_stats_w8(
        const int* __restrict__ csr, const int* __restrict__ cursor,
        const int* __restrict__ degi, const __half* __restrict__ Ph,
        const float* __restrict__ bias, __half* __restrict__ Qh,
        float* __restrict__ stPart, int N) {
    int t = threadIdx.x;
    int node = blockIdx.x * 16 + (t >> 4);
    int f = t & 15;                 // half2 index within the 64B row
    const __half2* rowb = (const __half2*)Ph; // row stride = 16 half2
    float q0 = 0.0f, q1 = 0.0f;
    if (node < N) {
        int end = cursor[node];
        int dg = degi[node];
        int k = end - dg;
        float2 sv = __half22float2(rowb[((size_t)node << 4) + f]);  // self loop
        float ax = sv.x, ay = sv.y;
        for (; k + 8 <= end; k += 8) {
            int s0 = csr[k],     s1 = csr[k + 1], s2 = csr[k + 2], s3 = csr[k + 3];
            int s4 = csr[k + 4], s5 = csr[k + 5], s6 = csr[k + 6], s7 = csr[k + 7];
            float2 v0 = __half22float2(rowb[((size_t)s0 << 4) + f]);
            float2 v1 = __half22float2(rowb[((size_t)s1 << 4) + f]);
            float2 v2 = __half22float2(rowb[((size_t)s2 << 4) + f]);
            float2 v3 = __half22float2(rowb[((size_t)s3 << 4) + f]);
            float2 v4 = __half22float2(rowb[((size_t)s4 << 4) + f]);
            float2 v5 = __half22float2(rowb[((size_t)s5 << 4) + f]);
            float2 v6 = __half22float2(rowb[((size_t)s6 << 4) + f]);
            float2 v7 = __half22float2(rowb[((size_t)s7 << 4) + f]);
            ax += ((v0.x + v1.x) + (v2.x + v3.x)) + ((v4.x + v5.x) + (v6.x + v7.x));
            ay += ((v0.y + v1.y) + (v2.y + v3.y)) + ((v4.y + v5.y) + (v6.y + v7.y));
        }
        for (; k + 4 <= end; k += 4) {
            int s0 = csr[k], s1 = csr[k + 1], s2 = csr[k + 2], s3 = csr[k + 3];
            float2 v0 = __half22float2(rowb[((size_t)s0 << 4) + f]);
            float2 v1 = __half22float2(rowb[((size_t)s1 << 4) + f]);
            float2 v2 = __half22float2(rowb[((size_t)s2 << 4) + f]);
            float2 v3 = __half22float2(rowb[((size_t)s3 << 4) + f]);
            ax += (v0.x + v1.x) + (v2.x + v3.x);
            ay += (v0.y + v1.y) + (v2.y + v3.y);
        }
        for (; k < end; ++k) {
            float2 v = __half22float2(rowb[((size_t)csr[k] << 4) + f]);
            ax += v.x; ay += v.y;
        }
        float dinv = rsqrtf((float)dg + 1.0f);
        if (f < 13) {
            int j0 = f << 1;
            q0 = fmaf(dinv, ax, bias[j0]);
            if (f < 12) q1 = fmaf(dinv, ay, bias[j0 + 1]);
            ((__half2*)Qh)[((size_t)node << 4) + f] = __floats2half2_rn(q0, q1);
        }
    }
    // ---- fused BN stats: reduce this block's 16 nodes ----
    float ls0 = q0, lq0 = q0 * q0, ls1 = q1, lq1 = q1 * q1;
    ls0 += __shfl_down(ls0, 32, 64); ls0 += __shfl_down(ls0, 16, 64);
    lq0 += __shfl_down(lq0, 32, 64); lq0 += __shfl_down(lq0, 16, 64);
    ls1 += __shfl_down(ls1, 32, 64); ls1 += __shfl_down(ls1, 16, 64);
    lq1 += __shfl_down(lq1, 32, 64); lq1 += __shfl_down(lq1, 16, 64);
    __shared__ float red[4][16][4];
    if ((t & 63) < 16) {
        int w = t >> 6;
        red[w][f][0] = ls0; red[w][f][1] = lq0;
        red[w][f][2] = ls1; red[w][f][3] = lq1;
    }
    __syncthreads();
    if (t < 64) {
        int ff = t >> 2, slot = t & 3;
        float tot = red[0][ff][slot] + red[1][ff][slot] + red[2][ff][slot] + red[3][ff][slot];
        int a = 2 * ff + (slot >> 1);
        if (a < D) atomicAdd(&stPart[(blockIdx.x & (NSLOT - 1)) * 50 + a + (slot & 1) * D], tot);
    }
}

// ------- layer2: reduce stPart -> mu/rstd; t = relu(bn(Qh)); Ph = half(dinv*(t@W2)) -------
__global__ __launch_bounds__(256) void bn_gemm_hp(
        const __half* __restrict__ Qh, const float* __restrict__ stPart, float invN,
        const float* __restrict__ g, const float* __restrict__ be,
        const float* __restrict__ W, const int* __restrict__ degi,
        __half* __restrict__ Ph, int N) {
    __shared__ float sW[D * D];
    __shared__ float sScale[D], sShift[D];
    __shared__ float sSum[2 * D];
    for (int j = threadIdx.x; j < D * D; j += blockDim.x) sW[j] = W[j];
    if (threadIdx.x < 2 * D) {
        float a = 0.0f;
        for (int k = 0; k < NSLOT; ++k) a += stPart[k * 50 + threadIdx.x];
        sSum[threadIdx.x] = a;
    }
    __syncthreads();
    if (threadIdx.x < D) {
        float m = sSum[threadIdx.x] * invN;
        float v = fmaxf(sSum[D + threadIdx.x] * invN - m * m, 0.0f);
        float sc = rsqrtf(v + EPS) * g[threadIdx.x];
        sScale[threadIdx.x] = sc;
        sShift[threadIdx.x] = be[threadIdx.x] - m * sc;
    }
    __syncthreads();
    int i = blockIdx.x * blockDim.x + threadIdx.x;
    if (i >= N) return;
    const __half2* qrow = (const __half2*)Qh + ((size_t)i << 4);
    float t[D];
#pragma unroll
    for (int ff = 0; ff < 13; ++ff) {
        float2 v = __half22float2(qrow[ff]);
        int j0 = ff << 1;
        t[j0] = fmaxf(0.0f, fmaf(v.x, sScale[j0], sShift[j0]));
        if (ff < 12) t[j0 + 1] = fmaxf(0.0f, fmaf(v.y, sScale[j0 + 1], sShift[j0 + 1]));
    }
    float dinv = rsqrtf((float)degi[i] + 1.0f);
    __half* row = Ph + (size_t)i * PH_STRIDE;
#pragma unroll
    for (int d = 0; d < D; ++d) {
        float acc = 0.0f;
#pragma unroll
        for (int k = 0; k < D; ++k) acc = fmaf(t[k], sW[k * D + d], acc);
        row[d] = __float2half(dinv * acc);
    }
#pragma unroll
    for (int d = D; d < PH_STRIDE; ++d) row[d] = __float2half(0.0f);
}

// ------- head: reduce stPart -> mu/rstd; t = relu(bn(Qh)); MLP; sigmoid -------
__global__ __launch_bounds__(256) void final_kernel_p(
        const __half* __restrict__ Qh, const float* __restrict__ stPart, float invN,
        const float* __restrict__ g, const float* __restrict__ be,
        const float* __restrict__ Wm1, const float* __restrict__ bm1,
        const float* __restrict__ Wm2, const float* __restrict__ bm2,
        float* __restrict__ out, int N) {
    __shared__ float sW1[D * 12];
    __shared__ float sb1[12], sW2[12];
    __shared__ float sScale[D], sShift[D];
    __shared__ float sSum[2 * D];
    __shared__ float sb2;
    for (int j = threadIdx.x; j < D * 12; j += blockDim.x) sW1[j] = Wm1[j];
    if (threadIdx.x < 12) {
        sb1[threadIdx.x] = bm1[threadIdx.x];
        sW2[threadIdx.x] = Wm2[threadIdx.x];
    }
    if (threadIdx.x < 2 * D) {
        float a = 0.0f;
        for (int k = 0; k < NSLOT; ++k) a += stPart[k * 50 + threadIdx.x];
        sSum[threadIdx.x] = a;
    }
    if (threadIdx.x == 0) sb2 = bm2[0];
    __syncthreads();
    if (threadIdx.x < D) {
        float m = sSum[threadIdx.x] * invN;
        float v = fmaxf(sSum[D + threadIdx.x] * invN - m * m, 0.0f);
        float sc = rsqrtf(v + EPS) * g[threadIdx.x];
        sScale[threadIdx.x] = sc;
        sShift[threadIdx.x] = be[threadIdx.x] - m * sc;
    }
    __syncthreads();
    int i = blockIdx.x * blockDim.x + threadIdx.x;
    if (i >= N) return;
    const __half2* qrow = (const __half2*)Qh + ((size_t)i << 4);
    float t[D];
#pragma unroll
    for (int ff = 0; ff < 13; ++ff) {
        float2 v = __half22float2(qrow[ff]);
        int j0 = ff << 1;
        t[j0] = fmaxf(0.0f, fmaf(v.x, sScale[j0], sShift[j0]));
        if (ff < 12) t[j0 + 1] = fmaxf(0.0f, fmaf(v.y, sScale[j0 + 1], sShift[j0 + 1]));
    }
    float z = sb2;
#pragma unroll
    for (int j = 0; j < 12; ++j) {
        float m = sb1[j];
#pragma unroll
        for (int k = 0; k < D; ++k) m = fmaf(t[k], sW1[k * 12 + j], m);
        m = fmaxf(0.0f, m);
        z = fmaf(m, sW2[j], z);
    }
    out[i] = 1.0f / (1.0f + expf(-z));
}

// ================= fallback kernels (atomic-scatter path, fp32) =================
__global__ void hist_kernel(const int* __restrict__ dst, int* __restrict__ degi, int E) {
    int e = blockIdx.x * blockDim.x + threadIdx.x;
    if (e < E) atomicAdd(&degi[dst[e]], 1);
}

__global__ __launch_bounds__(256) void embed_gemm1(
        const int* __restrict__ x, const float* __restrict__ emb,
        const float* __restrict__ W1, const int* __restrict__ degi,
        float* __restrict__ P, float* __restrict__ Qdup, int N) {
    __shared__ float sW[D * D];
    for (int j = threadIdx.x; j < D * D; j += blockDim.x) sW[j] = W1[j];
    __syncthreads();
    int i = blockIdx.x * blockDim.x + threadIdx.x;
    if (i >= N) return;
    const float* er = emb + (size_t)x[i] * D;
    float t[D];
#pragma unroll
    for (int k = 0; k < D; ++k) t[k] = er[k];
    float dinv = rsqrtf((float)degi[i] + 1.0f);
#pragma unroll
    for (int d = 0; d < D; ++d) {
        float acc = 0.0f;
#pragma unroll
        for (int k = 0; k < D; ++k) acc = fmaf(t[k], sW[k * D + d], acc);
        float v = dinv * acc;
        P[i * D + d] = v;
        if (Qdup) Qdup[i * D + d] = v;
    }
}

__global__ void scatter_kernel(const int* __restrict__ src, const int* __restrict__ dst,
                               const float* __restrict__ A, float* __restrict__ B, int E) {
    int idx = blockIdx.x * blockDim.x + threadIdx.x;
    int e = idx >> 5;
    int lane = idx & 31;
    if (e >= E || lane >= D) return;
    atomicAdd(&B[dst[e] * D + lane], A[src[e] * D + lane]);
}

__global__ __launch_bounds__(256) void transform_kernel(
        float* __restrict__ Q, const int* __restrict__ degi,
        const float* __restrict__ bias, int N) {
    int i = blockIdx.x * blockDim.x + threadIdx.x;
    if (i >= N) return;
    float dinv = rsqrtf((float)degi[i] + 1.0f);
#pragma unroll
    for (int d = 0; d < D; ++d)
        Q[i * D + d] = fmaf(dinv, Q[i * D + d], bias[d]);
}

__global__ __launch_bounds__(256) void stats_kernel(
        const float* __restrict__ Q, float* __restrict__ st, int N) {
    float ls[D], lq[D];
#pragma unroll
    for (int d = 0; d < D; ++d) { ls[d] = 0.0f; lq[d] = 0.0f; }
    for (int i = blockIdx.x * blockDim.x + threadIdx.x; i < N;
         i += gridDim.x * blockDim.x) {
#pragma unroll
        for (int d = 0; d < D; ++d) {
            float v = Q[i * D + d];
            ls[d] += v;
            lq[d] += v * v;
        }
    }
#pragma unroll
    for (int d = 0; d < D; ++d) {
        for (int off = 32; off > 0; off >>= 1) {
            ls[d] += __shfl_down(ls[d], off, 64);
            lq[d] += __shfl_down(lq[d], off, 64);
        }
    }
    __shared__ float red[4][2 * D];
    int wave = threadIdx.x >> 6;
    int lane = threadIdx.x & 63;
    if (lane == 0) {
#pragma unroll
        for (int d = 0; d < D; ++d) {
            red[wave][d] = ls[d];
            red[wave][D + d] = lq[d];
        }
    }
    __syncthreads();
    if (threadIdx.x < 2 * D) {
        float t = red[0][threadIdx.x] + red[1][threadIdx.x] +
                  red[2][threadIdx.x] + red[3][threadIdx.x];
        atomicAdd(&st[threadIdx.x], t);
    }
}

__global__ __launch_bounds__(256) void bn_gemm(
        const float* __restrict__ Qin, const float* __restrict__ st, float invN,
        const float* __restrict__ g, const float* __restrict__ be,
        const float* __restrict__ W, const int* __restrict__ degi,
        float* __restrict__ P, float* __restrict__ Qdup, int N) {
    __shared__ float sW[D * D];
    __shared__ float sScale[D], sShift[D];
    for (int j = threadIdx.x; j < D * D; j += blockDim.x) sW[j] = W[j];
    if (threadIdx.x < D) {
        float m = st[threadIdx.x] * invN;
        float v = fmaxf(st[D + threadIdx.x] * invN - m * m, 0.0f);
        float sc = rsqrtf(v + EPS) * g[threadIdx.x];
        sScale[threadIdx.x] = sc;
        sShift[threadIdx.x] = be[threadIdx.x] - m * sc;
    }
    __syncthreads();
    int i = blockIdx.x * blockDim.x + threadIdx.x;
    if (i >= N) return;
    float t[D];
#pragma unroll
    for (int d = 0; d < D; ++d)
        t[d] = fmaxf(0.0f, fmaf(Qin[i * D + d], sScale[d], sShift[d]));
    float dinv = rsqrtf((float)degi[i] + 1.0f);
#pragma unroll
    for (int d = 0; d < D; ++d) {
        float acc = 0.0f;
#pragma unroll
        for (int k = 0; k < D; ++k) acc = fmaf(t[k], sW[k * D + d], acc);
        float v = dinv * acc;
        P[i * D + d] = v;
        if (Qdup) Qdup[i * D + d] = v;
    }
}

__global__ __launch_bounds__(256) void final_kernel(
        const float* __restrict__ Q, const float* __restrict__ st, float invN,
        const float* __restrict__ g, const float* __restrict__ be,
        const float* __restrict__ Wm1, const float* __restrict__ bm1,
        const float* __restrict__ Wm2, const float* __restrict__ bm2,
        float* __restrict__ out, int N) {
    __shared__ float sW1[D * 12];
    __shared__ float sb1[12], sW2[12];
    __shared__ float sScale[D], sShift[D];
    __shared__ float sb2;
    for (int j = threadIdx.x; j < D * 12; j += blockDim.x) sW1[j] = Wm1[j];
    if (threadIdx.x < 12) {
        sb1[threadIdx.x] = bm1[threadIdx.x];
        sW2[threadIdx.x] = Wm2[threadIdx.x];
    }
    if (threadIdx.x < D) {
        float m = st[threadIdx.x] * invN;
        float v = fmaxf(st[D + threadIdx.x] * invN - m * m, 0.0f);
        float sc = rsqrtf(v + EPS) * g[threadIdx.x];
        sScale[threadIdx.x] = sc;
        sShift[threadIdx.x] = be[threadIdx.x] - m * sc;
    }
    if (threadIdx.x == 0) sb2 = bm2[0];
    __syncthreads();
    int i = blockIdx.x * blockDim.x + threadIdx.x;
    if (i >= N) return;
    float t[D];
#pragma unroll
    for (int d = 0; d < D; ++d)
        t[d] = fmaxf(0.0f, fmaf(Q[i * D + d], sScale[d], sShift[d]));
    float z = sb2;
#pragma unroll
    for (int j = 0; j < 12; ++j) {
        float m = sb1[j];
#pragma unroll
        for (int k = 0; k < D; ++k) m = fmaf(t[k], sW1[k * 12 + j], m);
        m = fmaxf(0.0f, m);
        z = fmaf(m, sW2[j], z);
    }
    out[i] = 1.0f / (1.0f + expf(-z));
}

extern "C" void kernel_launch(void* const* d_in, const int* in_sizes, int n_in,
                              void* d_out, int out_size, void* d_ws, size_t ws_size,
                              hipStream_t stream) {
    const int*   x    = (const int*)d_in[0];
    const int*   ei   = (const int*)d_in[1];
    const float* emb  = (const float*)d_in[2];
    const float* W1   = (const float*)d_in[3];
    const float* b1   = (const float*)d_in[4];
    const float* g1   = (const float*)d_in[5];
    const float* be1  = (const float*)d_in[6];
    const float* W2   = (const float*)d_in[7];
    const float* b2   = (const float*)d_in[8];
    const float* g2   = (const float*)d_in[9];
    const float* be2  = (const float*)d_in[10];
    const float* Wm1  = (const float*)d_in[11];
    const float* bm1  = (const float*)d_in[12];
    const float* Wm2  = (const float*)d_in[13];
    const float* bm2  = (const float*)d_in[14];
    float* out = (float*)d_out;

    int N = in_sizes[0];
    int E = in_sizes[1] / 2;
    const int* src = ei;
    const int* dst = ei + E;
    float invN = 1.0f / (float)N;

    int nbBin = (E + BIN_EDGES - 1) / BIN_EDGES;
    // words: degi N + cursor N + csr E + bCount 256 + hist2D nbBin*256 + Ph 16N + Qh 16N + stPart 6400
    size_t csrNeed = ((size_t)34 * N + E + 256 + (size_t)nbBin * NBK + 2 * NSLOT * 50) * 4;
    bool useCSR = (ws_size >= csrNeed) && (N <= NBK * 1024) && (nbBin <= 512) &&
                  ((size_t)E <= (size_t)16 * N) && (nbBin >= 25);

    int nbN  = (N + 255) / 256;
    int nbE  = (E + 255) / 256;
    int nbG  = (N + 15) / 16;            // 16 nodes per 256-thread block
    int nbS  = (int)(((long)E * 32 + 255) / 256);

    if (useCSR) {
        int*    degi    = (int*)d_ws;                   // N
        int*    cursor  = degi + N;                     // N
        int*    csr     = cursor + N;                   // E
        int*    bCount  = csr + E;                      // 256
        int*    hist2D  = bCount + NBK;                 // nbBin*256
        __half* Ph      = (__half*)(hist2D + (size_t)nbBin * NBK);   // N*32 halves
        __half* Qh      = Ph + (size_t)N * PH_STRIDE;   // N*32 halves
        float*  stP1    = (float*)(Qh + (size_t)N * PH_STRIDE);      // 64*50
        float*  stP2    = stP1 + NSLOT * 50;            // 64*50
        int*    binned  = (int*)Qh;                     // E ints (aliases Qh; dead before Qh written)

        int nbBkt = (N + 1023) / 1024;

        binA<<<nbBin, 256, 0, stream>>>(dst, hist2D, stP1, E);
        colscan<<<NBK, 512, 0, stream>>>(hist2D, bCount, nbBin);
        binB<<<nbBin, 256, 0, stream>>>(src, dst, hist2D, bCount, binned, E);
        fill_embed<<<nbBkt, 512, 0, stream>>>(binned, bCount, x, emb, W1,
                                              degi, cursor, csr, Ph, N);
        gather_stats_w8<<<nbG, 256, 0, stream>>>(csr, cursor, degi, Ph, b1, Qh, stP1, N);
        bn_gemm_hp<<<nbN, 256, 0, stream>>>(Qh, stP1, invN, g1, be1, W2, degi, Ph, N);
        gather_stats_w8<<<nbG, 256, 0, stream>>>(csr, cursor, degi, Ph, b2, Qh, stP2, N);
        final_kernel_p<<<nbN, 256, 0, stream>>>(Qh, stP2, invN, g2, be2, Wm1, bm1, Wm2, bm2, out, N);
    } else {
        // fallback: fp32 atomic-scatter path
        int*   degi  = (int*)d_ws;                  // N
        float* P     = (float*)(degi + N);          // N*D
        float* Q     = P + (size_t)N * D;           // N*D
        float* stats = Q + (size_t)N * D;           // 100
        float* st1 = stats;
        float* st2 = stats + 50;

        hipMemsetAsync(degi, 0, (size_t)N * sizeof(int), stream);
        hipMemsetAsync(stats, 0, 100 * sizeof(float), stream);

        hist_kernel<<<nbE, 256, 0, stream>>>(dst, degi, E);
        embed_gemm1<<<nbN, 256, 0, stream>>>(x, emb, W1, degi, P, Q, N);
        scatter_kernel<<<nbS, 256, 0, stream>>>(src, dst, P, Q, E);
        transform_kernel<<<nbN, 256, 0, stream>>>(Q, degi, b1, N);
        stats_kernel<<<STATS_BLOCKS, 256, 0, stream>>>(Q, st1, N);
        bn_gemm<<<nbN, 256, 0, stream>>>(Q, st1, invN, g1, be1, W2, degi, P, Q, N);
        scatter_kernel<<<nbS, 256, 0, stream>>>(src, dst, P, Q, E);
        transform_kernel<<<nbN, 256, 0, stream>>>(Q, degi, b2, N);
        stats_kernel<<<STATS_BLOCKS, 256, 0, stream>>>(Q, st2, N);
        final_kernel<<<nbN, 256, 0, stream>>>(Q, st2, invN, g2, be2, Wm1, bm1, Wm2, bm2, out, N);
    }
}

// Round 12
// 306.667 us; speedup vs baseline: 4.2431x; 1.0838x over previous
//
#include <hip/hip_runtime.h>
#include <hip/hip_fp16.h>
#include <math.h>

#define D 25
#define PH_STRIDE 32    // fp16 row padded to 32 elems = 64 B = one cache line
#define STATS_BLOCKS 512
#define NBKT 512        // buckets of 512 nodes
#define BSH 9
#define BMSK 511
#define BIN_EDGES 8192  // edges per bin block
#define SORT_CAP 10240  // LDS sort capacity per bucket (avg ~8.2k)
#define NSLOT 64        // replicated stat partial slots
#define EPS 1e-5f

// ---------------- binA: per-(block,bucket) histogram + stPart zeroing ----------------
__global__ __launch_bounds__(256) void binA(const int* __restrict__ dst,
                                            int* __restrict__ hist2D,
                                            float* __restrict__ stPart, int E) {
    if (blockIdx.x < 25) stPart[blockIdx.x * 256 + threadIdx.x] = 0.0f;
    __shared__ int h[NBKT];
    h[threadIdx.x] = 0;
    h[threadIdx.x + 256] = 0;
    __syncthreads();
    int base = blockIdx.x * BIN_EDGES;
#pragma unroll
    for (int j = 0; j < 32; ++j) {
        int idx = base + j * 256 + threadIdx.x;
        if (idx < E) atomicAdd(&h[dst[idx] >> BSH], 1);
    }
    __syncthreads();
    hist2D[blockIdx.x * NBKT + threadIdx.x] = h[threadIdx.x];
    hist2D[blockIdx.x * NBKT + threadIdx.x + 256] = h[threadIdx.x + 256];
}

// ------- colscan: per bucket, exclusive scan over blocks (in place) + total -------
__global__ __launch_bounds__(512) void colscan(int* __restrict__ hist2D,
                                               int* __restrict__ bCount, int nbBin) {
    __shared__ int s[512];
    int b = blockIdx.x;
    int j = threadIdx.x;
    int v = (j < nbBin) ? hist2D[j * NBKT + b] : 0;
    s[j] = v;
    __syncthreads();
    for (int off = 1; off < 512; off <<= 1) {
        int x = (j >= off) ? s[j - off] : 0;
        __syncthreads();
        s[j] += x;
        __syncthreads();
    }
    if (j < nbBin) hist2D[j * NBKT + b] = s[j] - v;   // exclusive prefix
    if (j == 0) bCount[b] = s[511];
}

// ------- binB (512 thr): inline scan of bCount for bases; write keys grouped by bucket -------
__global__ __launch_bounds__(512) void binB(const int* __restrict__ src,
                                            const int* __restrict__ dst,
                                            const int* __restrict__ hist2D,
                                            const int* __restrict__ bCount,
                                            int* __restrict__ binned, int E) {
    __shared__ int rank[NBKT], basew[NBKT], sc[NBKT];
    int t = threadIdx.x;
    int cnt = bCount[t];
    sc[t] = cnt;
    rank[t] = 0;
    __syncthreads();
    for (int off = 1; off < NBKT; off <<= 1) {
        int x = (t >= off) ? sc[t - off] : 0;
        __syncthreads();
        sc[t] += x;
        __syncthreads();
    }
    basew[t] = (sc[t] - cnt) + hist2D[blockIdx.x * NBKT + t];
    __syncthreads();
    int base = blockIdx.x * BIN_EDGES;
#pragma unroll
    for (int j = 0; j < 16; ++j) {
        int idx = base + j * 512 + t;
        if (idx < E) {
            int d = dst[idx];
            int b = d >> BSH;
            int r = atomicAdd(&rank[b], 1);
            binned[basew[b] + r] = (src[idx] << BSH) | (d & BMSK);
        }
    }
}

// ------- bucket_fill (512 thr): sort bucket b (512 nodes) in LDS, coalesced csr writeout -------
__global__ __launch_bounds__(512) void bucket_fill(
        const int* __restrict__ binned, const int* __restrict__ bCount,
        int* __restrict__ degi, int* __restrict__ cursor, int* __restrict__ csr, int N) {
    int b = blockIdx.x;
    int nodeBase = b << BSH;
    if (nodeBase >= N) return;
    __shared__ int h[NBKT];
    __shared__ int s2[512];
    __shared__ int sorted[SORT_CAP];
    int t = threadIdx.x;
    // parallel reduce of bCount[0..b-1] into base
    s2[t] = (t < b) ? bCount[t] : 0;
    __syncthreads();
    for (int off = 256; off > 0; off >>= 1) {
        if (t < off) s2[t] += s2[t + off];
        __syncthreads();
    }
    int s = s2[0];
    __syncthreads();
    h[t] = 0;
    __syncthreads();
    int cnt = bCount[b];
    int e = s + cnt;
    // degree histogram
    for (int k = s + t; k < e; k += 512)
        atomicAdd(&h[binned[k] & BMSK], 1);
    __syncthreads();
    int dg = h[t];
    int node = nodeBase + t;
    if (node < N) degi[node] = dg;
    s2[t] = dg;
    __syncthreads();
    for (int off = 1; off < 512; off <<= 1) {
        int x = (t >= off) ? s2[t - off] : 0;
        __syncthreads();
        s2[t] += x;
        __syncthreads();
    }
    int start = s2[t] - dg;            // local row start
    h[t] = start;                      // becomes cursor for fill
    if (node < N) cursor[node] = s + s2[t];   // global row end
    __syncthreads();
    if (cnt <= SORT_CAP) {
        // scatter into LDS, then coalesced writeout
        for (int k = s + t; k < e; k += 512) {
            int key = binned[k];
            int p = atomicAdd(&h[key & BMSK], 1);
            sorted[p] = key >> BSH;
        }
        __syncthreads();
        for (int j = t; j < cnt; j += 512)
            csr[s + j] = sorted[j];
    } else {
        // overflow fallback: direct global scatter
        for (int k = s + t; k < e; k += 512) {
            int key = binned[k];
            int p = atomicAdd(&h[key & BMSK], 1);
            csr[s + p] = key >> BSH;
        }
    }
}

// ------------- layer1 (fp16 rows): Ph = half(dinv * (emb[x] @ W1)), stride 32, pads=0 -------------
__global__ __launch_bounds__(256) void embed_gemm1_h(
        const int* __restrict__ x, const float* __restrict__ emb,
        const float* __restrict__ W1, const int* __restrict__ degi,
        __half* __restrict__ Ph, int N) {
    __shared__ float sW[D * D];
    for (int j = threadIdx.x; j < D * D; j += blockDim.x) sW[j] = W1[j];
    __syncthreads();
    int i = blockIdx.x * blockDim.x + threadIdx.x;
    if (i >= N) return;
    const float* er = emb + (size_t)x[i] * D;
    float t[D];
#pragma unroll
    for (int k = 0; k < D; ++k) t[k] = er[k];
    float dinv = rsqrtf((float)degi[i] + 1.0f);
    __half* row = Ph + (size_t)i * PH_STRIDE;
#pragma unroll
    for (int d = 0; d < D; ++d) {
        float acc = 0.0f;
#pragma unroll
        for (int k = 0; k < D; ++k) acc = fmaf(t[k], sW[k * D + d], acc);
        row[d] = __float2half(dinv * acc);
    }
#pragma unroll
    for (int d = D; d < PH_STRIDE; ++d) row[d] = __float2half(0.0f);
}

// ------- gather + fused BN-stats: 16-lane walk per node, 8 edges in flight;
//         Q stored as fp16 rows (stride 32); stPart[blockIdx%64][50] -------
__global__ __launch_bounds__(256) void gather_stats_w8(
        const int* __restrict__ csr, const int* __restrict__ cursor,
        const int* __restrict__ degi, const __half* __restrict__ Ph,
        const float* __restrict__ bias, __half* __restrict__ Qh,
        float* __restrict__ stPart, int N) {
    int t = threadIdx.x;
    int node = blockIdx.x * 16 + (t >> 4);
    int f = t & 15;                 // half2 index within the 64B row
    const __half2* rowb = (const __half2*)Ph; // row stride = 16 half2
    float q0 = 0.0f, q1 = 0.0f;
    if (node < N) {
        int end = cursor[node];
        int dg = degi[node];
        int k = end - dg;
        float2 sv = __half22float2(rowb[((size_t)node << 4) + f]);  // self loop
        float ax = sv.x, ay = sv.y;
        for (; k + 8 <= end; k += 8) {
            int s0 = csr[k],     s1 = csr[k + 1], s2 = csr[k + 2], s3 = csr[k + 3];
            int s4 = csr[k + 4], s5 = csr[k + 5], s6 = csr[k + 6], s7 = csr[k + 7];
            float2 v0 = __half22float2(rowb[((size_t)s0 << 4) + f]);
            float2 v1 = __half22float2(rowb[((size_t)s1 << 4) + f]);
            float2 v2 = __half22float2(rowb[((size_t)s2 << 4) + f]);
            float2 v3 = __half22float2(rowb[((size_t)s3 << 4) + f]);
            float2 v4 = __half22float2(rowb[((size_t)s4 << 4) + f]);
            float2 v5 = __half22float2(rowb[((size_t)s5 << 4) + f]);
            float2 v6 = __half22float2(rowb[((size_t)s6 << 4) + f]);
            float2 v7 = __half22float2(rowb[((size_t)s7 << 4) + f]);
            ax += ((v0.x + v1.x) + (v2.x + v3.x)) + ((v4.x + v5.x) + (v6.x + v7.x));
            ay += ((v0.y + v1.y) + (v2.y + v3.y)) + ((v4.y + v5.y) + (v6.y + v7.y));
        }
        for (; k + 4 <= end; k += 4) {
            int s0 = csr[k], s1 = csr[k + 1], s2 = csr[k + 2], s3 = csr[k + 3];
            float2 v0 = __half22float2(rowb[((size_t)s0 << 4) + f]);
            float2 v1 = __half22float2(rowb[((size_t)s1 << 4) + f]);
            float2 v2 = __half22float2(rowb[((size_t)s2 << 4) + f]);
            float2 v3 = __half22float2(rowb[((size_t)s3 << 4) + f]);
            ax += (v0.x + v1.x) + (v2.x + v3.x);
            ay += (v0.y + v1.y) + (v2.y + v3.y);
        }
        for (; k < end; ++k) {
            float2 v = __half22float2(rowb[((size_t)csr[k] << 4) + f]);
            ax += v.x; ay += v.y;
        }
        float dinv = rsqrtf((float)dg + 1.0f);
        if (f < 13) {
            int j0 = f << 1;
            q0 = fmaf(dinv, ax, bias[j0]);
            if (f < 12) q1 = fmaf(dinv, ay, bias[j0 + 1]);
            ((__half2*)Qh)[((size_t)node << 4) + f] = __floats2half2_rn(q0, q1);
        }
    }
    // ---- fused BN stats ----
    float ls0 = q0, lq0 = q0 * q0, ls1 = q1, lq1 = q1 * q1;
    ls0 += __shfl_down(ls0, 32, 64); ls0 += __shfl_down(ls0, 16, 64);
    lq0 += __shfl_down(lq0, 32, 64); lq0 += __shfl_down(lq0, 16, 64);
    ls1 += __shfl_down(ls1, 32, 64); ls1 += __shfl_down(ls1, 16, 64);
    lq1 += __shfl_down(lq1, 32, 64); lq1 += __shfl_down(lq1, 16, 64);
    __shared__ float red[4][16][4];
    if ((t & 63) < 16) {
        int w = t >> 6;
        red[w][f][0] = ls0; red[w][f][1] = lq0;
        red[w][f][2] = ls1; red[w][f][3] = lq1;
    }
    __syncthreads();
    if (t < 64) {
        int ff = t >> 2, slot = t & 3;
        float tot = red[0][ff][slot] + red[1][ff][slot] + red[2][ff][slot] + red[3][ff][slot];
        int a = 2 * ff + (slot >> 1);
        if (a < D) atomicAdd(&stPart[(blockIdx.x & (NSLOT - 1)) * 50 + a + (slot & 1) * D], tot);
    }
}

// ------- layer2: reduce stPart -> mu/rstd; t = relu(bn(Qh)); Ph = half(dinv*(t@W2)) -------
__global__ __launch_bounds__(256) void bn_gemm_hp(
        const __half* __restrict__ Qh, const float* __restrict__ stPart, float invN,
        const float* __restrict__ g, const float* __restrict__ be,
        const float* __restrict__ W, const int* __restrict__ degi,
        __half* __restrict__ Ph, int N) {
    __shared__ float sW[D * D];
    __shared__ float sScale[D], sShift[D];
    __shared__ float sSum[2 * D];
    for (int j = threadIdx.x; j < D * D; j += blockDim.x) sW[j] = W[j];
    if (threadIdx.x < 2 * D) {
        float a = 0.0f;
        for (int k = 0; k < NSLOT; ++k) a += stPart[k * 50 + threadIdx.x];
        sSum[threadIdx.x] = a;
    }
    __syncthreads();
    if (threadIdx.x < D) {
        float m = sSum[threadIdx.x] * invN;
        float v = fmaxf(sSum[D + threadIdx.x] * invN - m * m, 0.0f);
        float sc = rsqrtf(v + EPS) * g[threadIdx.x];
        sScale[threadIdx.x] = sc;
        sShift[threadIdx.x] = be[threadIdx.x] - m * sc;
    }
    __syncthreads();
    int i = blockIdx.x * blockDim.x + threadIdx.x;
    if (i >= N) return;
    const __half2* qrow = (const __half2*)Qh + ((size_t)i << 4);
    float t[D];
#pragma unroll
    for (int ff = 0; ff < 13; ++ff) {
        float2 v = __half22float2(qrow[ff]);
        int j0 = ff << 1;
        t[j0] = fmaxf(0.0f, fmaf(v.x, sScale[j0], sShift[j0]));
        if (ff < 12) t[j0 + 1] = fmaxf(0.0f, fmaf(v.y, sScale[j0 + 1], sShift[j0 + 1]));
    }
    float dinv = rsqrtf((float)degi[i] + 1.0f);
    __half* row = Ph + (size_t)i * PH_STRIDE;
#pragma unroll
    for (int d = 0; d < D; ++d) {
        float acc = 0.0f;
#pragma unroll
        for (int k = 0; k < D; ++k) acc = fmaf(t[k], sW[k * D + d], acc);
        row[d] = __float2half(dinv * acc);
    }
#pragma unroll
    for (int d = D; d < PH_STRIDE; ++d) row[d] = __float2half(0.0f);
}

// ------- head: reduce stPart -> mu/rstd; t = relu(bn(Qh)); MLP; sigmoid -------
__global__ __launch_bounds__(256) void final_kernel_p(
        const __half* __restrict__ Qh, const float* __restrict__ stPart, float invN,
        const float* __restrict__ g, const float* __restrict__ be,
        const float* __restrict__ Wm1, const float* __restrict__ bm1,
        const float* __restrict__ Wm2, const float* __restrict__ bm2,
        float* __restrict__ out, int N) {
    __shared__ float sW1[D * 12];
    __shared__ float sb1[12], sW2[12];
    __shared__ float sScale[D], sShift[D];
    __shared__ float sSum[2 * D];
    __shared__ float sb2;
    for (int j = threadIdx.x; j < D * 12; j += blockDim.x) sW1[j] = Wm1[j];
    if (threadIdx.x < 12) {
        sb1[threadIdx.x] = bm1[threadIdx.x];
        sW2[threadIdx.x] = Wm2[threadIdx.x];
    }
    if (threadIdx.x < 2 * D) {
        float a = 0.0f;
        for (int k = 0; k < NSLOT; ++k) a += stPart[k * 50 + threadIdx.x];
        sSum[threadIdx.x] = a;
    }
    if (threadIdx.x == 0) sb2 = bm2[0];
    __syncthreads();
    if (threadIdx.x < D) {
        float m = sSum[threadIdx.x] * invN;
        float v = fmaxf(sSum[D + threadIdx.x] * invN - m * m, 0.0f);
        float sc = rsqrtf(v + EPS) * g[threadIdx.x];
        sScale[threadIdx.x] = sc;
        sShift[threadIdx.x] = be[threadIdx.x] - m * sc;
    }
    __syncthreads();
    int i = blockIdx.x * blockDim.x + threadIdx.x;
    if (i >= N) return;
    const __half2* qrow = (const __half2*)Qh + ((size_t)i << 4);
    float t[D];
#pragma unroll
    for (int ff = 0; ff < 13; ++ff) {
        float2 v = __half22float2(qrow[ff]);
        int j0 = ff << 1;
        t[j0] = fmaxf(0.0f, fmaf(v.x, sScale[j0], sShift[j0]));
        if (ff < 12) t[j0 + 1] = fmaxf(0.0f, fmaf(v.y, sScale[j0 + 1], sShift[j0 + 1]));
    }
    float z = sb2;
#pragma unroll
    for (int j = 0; j < 12; ++j) {
        float m = sb1[j];
#pragma unroll
        for (int k = 0; k < D; ++k) m = fmaf(t[k], sW1[k * 12 + j], m);
        m = fmaxf(0.0f, m);
        z = fmaf(m, sW2[j], z);
    }
    out[i] = 1.0f / (1.0f + expf(-z));
}

// ================= fallback kernels (atomic-scatter path, fp32) =================
__global__ void hist_kernel(const int* __restrict__ dst, int* __restrict__ degi, int E) {
    int e = blockIdx.x * blockDim.x + threadIdx.x;
    if (e < E) atomicAdd(&degi[dst[e]], 1);
}

__global__ __launch_bounds__(256) void embed_gemm1(
        const int* __restrict__ x, const float* __restrict__ emb,
        const float* __restrict__ W1, const int* __restrict__ degi,
        float* __restrict__ P, float* __restrict__ Qdup, int N) {
    __shared__ float sW[D * D];
    for (int j = threadIdx.x; j < D * D; j += blockDim.x) sW[j] = W1[j];
    __syncthreads();
    int i = blockIdx.x * blockDim.x + threadIdx.x;
    if (i >= N) return;
    const float* er = emb + (size_t)x[i] * D;
    float t[D];
#pragma unroll
    for (int k = 0; k < D; ++k) t[k] = er[k];
    float dinv = rsqrtf((float)degi[i] + 1.0f);
#pragma unroll
    for (int d = 0; d < D; ++d) {
        float acc = 0.0f;
#pragma unroll
        for (int k = 0; k < D; ++k) acc = fmaf(t[k], sW[k * D + d], acc);
        float v = dinv * acc;
        P[i * D + d] = v;
        if (Qdup) Qdup[i * D + d] = v;
    }
}

__global__ void scatter_kernel(const int* __restrict__ src, const int* __restrict__ dst,
                               const float* __restrict__ A, float* __restrict__ B, int E) {
    int idx = blockIdx.x * blockDim.x + threadIdx.x;
    int e = idx >> 5;
    int lane = idx & 31;
    if (e >= E || lane >= D) return;
    atomicAdd(&B[dst[e] * D + lane], A[src[e] * D + lane]);
}

__global__ __launch_bounds__(256) void transform_kernel(
        float* __restrict__ Q, const int* __restrict__ degi,
        const float* __restrict__ bias, int N) {
    int i = blockIdx.x * blockDim.x + threadIdx.x;
    if (i >= N) return;
    float dinv = rsqrtf((float)degi[i] + 1.0f);
#pragma unroll
    for (int d = 0; d < D; ++d)
        Q[i * D + d] = fmaf(dinv, Q[i * D + d], bias[d]);
}

__global__ __launch_bounds__(256) void stats_kernel(
        const float* __restrict__ Q, float* __restrict__ st, int N) {
    float ls[D], lq[D];
#pragma unroll
    for (int d = 0; d < D; ++d) { ls[d] = 0.0f; lq[d] = 0.0f; }
    for (int i = blockIdx.x * blockDim.x + threadIdx.x; i < N;
         i += gridDim.x * blockDim.x) {
#pragma unroll
        for (int d = 0; d < D; ++d) {
            float v = Q[i * D + d];
            ls[d] += v;
            lq[d] += v * v;
        }
    }
#pragma unroll
    for (int d = 0; d < D; ++d) {
        for (int off = 32; off > 0; off >>= 1) {
            ls[d] += __shfl_down(ls[d], off, 64);
            lq[d] += __shfl_down(lq[d], off, 64);
        }
    }
    __shared__ float red[4][2 * D];
    int wave = threadIdx.x >> 6;
    int lane = threadIdx.x & 63;
    if (lane == 0) {
#pragma unroll
        for (int d = 0; d < D; ++d) {
            red[wave][d] = ls[d];
            red[wave][D + d] = lq[d];
        }
    }
    __syncthreads();
    if (threadIdx.x < 2 * D) {
        float t = red[0][threadIdx.x] + red[1][threadIdx.x] +
                  red[2][threadIdx.x] + red[3][threadIdx.x];
        atomicAdd(&st[threadIdx.x], t);
    }
}

__global__ __launch_bounds__(256) void bn_gemm(
        const float* __restrict__ Qin, const float* __restrict__ st, float invN,
        const float* __restrict__ g, const float* __restrict__ be,
        const float* __restrict__ W, const int* __restrict__ degi,
        float* __restrict__ P, float* __restrict__ Qdup, int N) {
    __shared__ float sW[D * D];
    __shared__ float sScale[D], sShift[D];
    for (int j = threadIdx.x; j < D * D; j += blockDim.x) sW[j] = W[j];
    if (threadIdx.x < D) {
        float m = st[threadIdx.x] * invN;
        float v = fmaxf(st[D + threadIdx.x] * invN - m * m, 0.0f);
        float sc = rsqrtf(v + EPS) * g[threadIdx.x];
        sScale[threadIdx.x] = sc;
        sShift[threadIdx.x] = be[threadIdx.x] - m * sc;
    }
    __syncthreads();
    int i = blockIdx.x * blockDim.x + threadIdx.x;
    if (i >= N) return;
    float t[D];
#pragma unroll
    for (int d = 0; d < D; ++d)
        t[d] = fmaxf(0.0f, fmaf(Qin[i * D + d], sScale[d], sShift[d]));
    float dinv = rsqrtf((float)degi[i] + 1.0f);
#pragma unroll
    for (int d = 0; d < D; ++d) {
        float acc = 0.0f;
#pragma unroll
        for (int k = 0; k < D; ++k) acc = fmaf(t[k], sW[k * D + d], acc);
        float v = dinv * acc;
        P[i * D + d] = v;
        if (Qdup) Qdup[i * D + d] = v;
    }
}

__global__ __launch_bounds__(256) void final_kernel(
        const float* __restrict__ Q, const float* __restrict__ st, float invN,
        const float* __restrict__ g, const float* __restrict__ be,
        const float* __restrict__ Wm1, const float* __restrict__ bm1,
        const float* __restrict__ Wm2, const float* __restrict__ bm2,
        float* __restrict__ out, int N) {
    __shared__ float sW1[D * 12];
    __shared__ float sb1[12], sW2[12];
    __shared__ float sScale[D], sShift[D];
    __shared__ float sb2;
    for (int j = threadIdx.x; j < D * 12; j += blockDim.x) sW1[j] = Wm1[j];
    if (threadIdx.x < 12) {
        sb1[threadIdx.x] = bm1[threadIdx.x];
        sW2[threadIdx.x] = Wm2[threadIdx.x];
    }
    if (threadIdx.x < D) {
        float m = st[threadIdx.x] * invN;
        float v = fmaxf(st[D + threadIdx.x] * invN - m * m, 0.0f);
        float sc = rsqrtf(v + EPS) * g[threadIdx.x];
        sScale[threadIdx.x] = sc;
        sShift[threadIdx.x] = be[threadIdx.x] - m * sc;
    }
    if (threadIdx.x == 0) sb2 = bm2[0];
    __syncthreads();
    int i = blockIdx.x * blockDim.x + threadIdx.x;
    if (i >= N) return;
    float t[D];
#pragma unroll
    for (int d = 0; d < D; ++d)
        t[d] = fmaxf(0.0f, fmaf(Q[i * D + d], sScale[d], sShift[d]));
    float z = sb2;
#pragma unroll
    for (int j = 0; j < 12; ++j) {
        float m = sb1[j];
#pragma unroll
        for (int k = 0; k < D; ++k) m = fmaf(t[k], sW1[k * 12 + j], m);
        m = fmaxf(0.0f, m);
        z = fmaf(m, sW2[j], z);
    }
    out[i] = 1.0f / (1.0f + expf(-z));
}

extern "C" void kernel_launch(void* const* d_in, const int* in_sizes, int n_in,
                              void* d_out, int out_size, void* d_ws, size_t ws_size,
                              hipStream_t stream) {
    const int*   x    = (const int*)d_in[0];
    const int*   ei   = (const int*)d_in[1];
    const float* emb  = (const float*)d_in[2];
    const float* W1   = (const float*)d_in[3];
    const float* b1   = (const float*)d_in[4];
    const float* g1   = (const float*)d_in[5];
    const float* be1  = (const float*)d_in[6];
    const float* W2   = (const float*)d_in[7];
    const float* b2   = (const float*)d_in[8];
    const float* g2   = (const float*)d_in[9];
    const float* be2  = (const float*)d_in[10];
    const float* Wm1  = (const float*)d_in[11];
    const float* bm1  = (const float*)d_in[12];
    const float* Wm2  = (const float*)d_in[13];
    const float* bm2  = (const float*)d_in[14];
    float* out = (float*)d_out;

    int N = in_sizes[0];
    int E = in_sizes[1] / 2;
    const int* src = ei;
    const int* dst = ei + E;
    float invN = 1.0f / (float)N;

    int nbBin = (E + BIN_EDGES - 1) / BIN_EDGES;
    // words: degi N + cursor N + csr E + bCount 512 + hist2D nbBin*512 + Ph 16N + Qh 16N + stPart 6400
    size_t csrNeed = ((size_t)34 * N + E + 512 + (size_t)nbBin * NBKT + 2 * NSLOT * 50) * 4;
    bool useCSR = (ws_size >= csrNeed) && (N <= NBKT * 512) && (nbBin <= 512) &&
                  ((size_t)E <= (size_t)16 * N) && (nbBin >= 25);

    int nbN  = (N + 255) / 256;
    int nbE  = (E + 255) / 256;
    int nbG  = (N + 15) / 16;            // 16 nodes per 256-thread block
    int nbS  = (int)(((long)E * 32 + 255) / 256);

    if (useCSR) {
        int*    degi    = (int*)d_ws;                   // N
        int*    cursor  = degi + N;                     // N
        int*    csr     = cursor + N;                   // E
        int*    bCount  = csr + E;                      // 512
        int*    hist2D  = bCount + NBKT;                // nbBin*512
        __half* Ph      = (__half*)(hist2D + (size_t)nbBin * NBKT);  // N*32 halves
        __half* Qh      = Ph + (size_t)N * PH_STRIDE;   // N*32 halves
        float*  stP1    = (float*)(Qh + (size_t)N * PH_STRIDE);      // 64*50
        float*  stP2    = stP1 + NSLOT * 50;            // 64*50
        int*    binned  = (int*)Qh;                     // E ints (aliases Qh; dead before Qh written)

        int nbBkt = (N + 511) / 512;

        binA<<<nbBin, 256, 0, stream>>>(dst, hist2D, stP1, E);
        colscan<<<NBKT, 512, 0, stream>>>(hist2D, bCount, nbBin);
        binB<<<nbBin, 512, 0, stream>>>(src, dst, hist2D, bCount, binned, E);
        bucket_fill<<<nbBkt, 512, 0, stream>>>(binned, bCount, degi, cursor, csr, N);
        embed_gemm1_h<<<nbN, 256, 0, stream>>>(x, emb, W1, degi, Ph, N);
        gather_stats_w8<<<nbG, 256, 0, stream>>>(csr, cursor, degi, Ph, b1, Qh, stP1, N);
        bn_gemm_hp<<<nbN, 256, 0, stream>>>(Qh, stP1, invN, g1, be1, W2, degi, Ph, N);
        gather_stats_w8<<<nbG, 256, 0, stream>>>(csr, cursor, degi, Ph, b2, Qh, stP2, N);
        final_kernel_p<<<nbN, 256, 0, stream>>>(Qh, stP2, invN, g2, be2, Wm1, bm1, Wm2, bm2, out, N);
    } else {
        // fallback: fp32 atomic-scatter path
        int*   degi  = (int*)d_ws;                  // N
        float* P     = (float*)(degi + N);          // N*D
        float* Q     = P + (size_t)N * D;           // N*D
        float* stats = Q + (size_t)N * D;           // 100
        float* st1 = stats;
        float* st2 = stats + 50;

        hipMemsetAsync(degi, 0, (size_t)N * sizeof(int), stream);
        hipMemsetAsync(stats, 0, 100 * sizeof(float), stream);

        hist_kernel<<<nbE, 256, 0, stream>>>(dst, degi, E);
        embed_gemm1<<<nbN, 256, 0, stream>>>(x, emb, W1, degi, P, Q, N);
        scatter_kernel<<<nbS, 256, 0, stream>>>(src, dst, P, Q, E);
        transform_kernel<<<nbN, 256, 0, stream>>>(Q, degi, b1, N);
        stats_kernel<<<STATS_BLOCKS, 256, 0, stream>>>(Q, st1, N);
        bn_gemm<<<nbN, 256, 0, stream>>>(Q, st1, invN, g1, be1, W2, degi, P, Q, N);
        scatter_kernel<<<nbS, 256, 0, stream>>>(src, dst, P, Q, E);
        transform_kernel<<<nbN, 256, 0, stream>>>(Q, degi, b2, N);
        stats_kernel<<<STATS_BLOCKS, 256, 0, stream>>>(Q, st2, N);
        final_kernel<<<nbN, 256, 0, stream>>>(Q, st2, invN, g2, be2, Wm1, bm1, Wm2, bm2, out, N);
    }
}